// Round 1
// baseline (675.320 us; speedup 1.0000x reference)
//
#include <hip/hip_runtime.h>
#include <math.h>

#define NU 3
#define BB 16
#define NN 1024
#define DD 256
#define MM (BB*NN)      // 16384 tokens per util
#define NPAIR 6

// workspace layout (float element offsets)
#define OFF_UNARY  0
#define OFF_INVXS  (OFF_UNARY + NU*MM)
#define OFF_INVXP  (OFF_INVXS + NU*MM)
#define OFF_INVYP  (OFF_INVXP + NPAIR*MM)
#define OFF_YBAR   (OFF_INVYP + NPAIR*MM)          // bars contiguous for one memset
#define OFF_XPBAR  (OFF_YBAR + NU*BB*DD)
#define OFF_YPBAR  (OFF_XPBAR + NPAIR*BB*DD)
#define OFF_PROJS  (OFF_YPBAR + NPAIR*BB*DD)
#define OFF_PROJX  (OFF_PROJS + NU*BB*DD)
#define OFF_PROJY  (OFF_PROJX + NPAIR*BB*DD)
#define OFF_CSS    (OFF_PROJY + NPAIR*BB*DD)
#define OFF_CSX    (OFF_CSS + NU*BB)
#define OFF_CSY    (OFF_CSX + NPAIR*BB)
#define OFF_SELFP  (OFF_CSY + NPAIR*BB)
#define OFF_POTX   (OFF_SELFP + NU*MM)
#define OFF_POTY   (OFF_POTX + NPAIR*MM)
#define WS_FLOATS  (OFF_POTY + NPAIR*MM)

__device__ __forceinline__ int pair_j_of(int i, int idx) {
    // ordered pairs p = i*2 + idx, j ascending over {0,1,2}\{i}
    return idx == 0 ? (i == 0 ? 1 : 0) : (i == 2 ? 1 : 2);
}
__device__ __forceinline__ const float* selU(int u, const float* u0, const float* u1, const float* u2) {
    return u == 0 ? u0 : (u == 1 ? u1 : u2);
}

// ---------------------------------------------------------------------------
// Pass 1: 21 GEMM-like tasks (16384 x 256 x 256) with fused per-token epilogue.
// task 0..2  : unary (relu(e)*wr reduce)                     -> unary[u][row]
// task 3..5  : self X  (store 1/||e||)                       -> inv_xs
// task 6..8  : self Y  (accumulate normalized mean)          -> Ybar
// task 9..14 : cross X pair p (inv + bar)                    -> inv_xp, Xpbar
// task 15..20: cross Y pair p (inv + bar)                    -> inv_yp, Ypbar
// Block: 64 tokens x 256 e, 256 threads, 8x8 micro-tile, K-chunks of 32.
// ---------------------------------------------------------------------------
__global__ __launch_bounds__(256) void pass1_kernel(
    const float* __restrict__ u0, const float* __restrict__ u1, const float* __restrict__ u2,
    const float* __restrict__ Wu,  const float* __restrict__ bu,
    const float* __restrict__ wr,  const float* __restrict__ br,
    const float* __restrict__ Wsx, const float* __restrict__ bsx,
    const float* __restrict__ Wsy, const float* __restrict__ bsy,
    const float* __restrict__ Wpx, const float* __restrict__ bpx,
    const float* __restrict__ Wpy, const float* __restrict__ bpy,
    float* __restrict__ ws)
{
    __shared__ float Us[64][33];    // token x k tile
    __shared__ float Wt[256][33];   // e x k tile

    const int tid  = threadIdx.x;
    const int task = blockIdx.y;
    const int row0 = blockIdx.x * 64;
    const int b    = row0 >> 10;    // 64 | 1024 so batch is uniform per block

    int kind, uu = 0, pp = 0;
    const float *W, *bias, *src;
    if (task < 3)       { kind = 0; uu = task;      W = Wu  + uu*DD*DD; bias = bu  + uu*DD; src = selU(uu,u0,u1,u2); }
    else if (task < 6)  { kind = 1; uu = task - 3;  W = Wsx + uu*DD*DD; bias = bsx + uu*DD; src = selU(uu,u0,u1,u2); }
    else if (task < 9)  { kind = 2; uu = task - 6;  W = Wsy + uu*DD*DD; bias = bsy + uu*DD; src = selU(uu,u0,u1,u2); }
    else if (task < 15) { kind = 3; pp = task - 9;  const int i = pp>>1, j = pair_j_of(i, pp&1);
                          W = Wpx + (i*NU+j)*DD*DD; bias = bpx + (i*NU+j)*DD; src = selU(i,u0,u1,u2); }
    else                { kind = 4; pp = task - 15; const int i = pp>>1, j = pair_j_of(i, pp&1);
                          W = Wpy + (i*NU+j)*DD*DD; bias = bpy + (i*NU+j)*DD; src = selU(j,u0,u1,u2); }

    const int et = tid >> 3;        // e-group 0..31, e = et*8 + ev
    const int tt = tid & 7;         // token-group 0..7, token = tt*8 + a
    const int lr = tid >> 3;        // load row
    const int lc = (tid & 7) * 4;   // load col (floats)

    float acc[8][8];
    #pragma unroll
    for (int a = 0; a < 8; ++a)
        #pragma unroll
        for (int e = 0; e < 8; ++e) acc[a][e] = 0.f;

    for (int kc = 0; kc < 8; ++kc) {
        // U tile: 64 x 32
        #pragma unroll
        for (int h = 0; h < 2; ++h) {
            const int r = lr + h*32;
            const float4 v = *reinterpret_cast<const float4*>(src + (size_t)(row0 + r)*DD + kc*32 + lc);
            Us[r][lc+0]=v.x; Us[r][lc+1]=v.y; Us[r][lc+2]=v.z; Us[r][lc+3]=v.w;
        }
        // W tile: 256 x 32
        #pragma unroll
        for (int ps = 0; ps < 8; ++ps) {
            const int e = ps*32 + lr;
            const float4 v = *reinterpret_cast<const float4*>(W + (size_t)e*DD + kc*32 + lc);
            Wt[e][lc+0]=v.x; Wt[e][lc+1]=v.y; Wt[e][lc+2]=v.z; Wt[e][lc+3]=v.w;
        }
        __syncthreads();
        #pragma unroll 4
        for (int k = 0; k < 32; ++k) {
            float wv[8], uv[8];
            #pragma unroll
            for (int e = 0; e < 8; ++e) wv[e] = Wt[et*8+e][k];
            #pragma unroll
            for (int a = 0; a < 8; ++a) uv[a] = Us[tt*8+a][k];
            #pragma unroll
            for (int a = 0; a < 8; ++a)
                #pragma unroll
                for (int e = 0; e < 8; ++e) acc[a][e] = fmaf(uv[a], wv[e], acc[a][e]);
        }
        __syncthreads();
    }

    // add bias
    #pragma unroll
    for (int e = 0; e < 8; ++e) {
        const float bv = bias[et*8+e];
        #pragma unroll
        for (int a = 0; a < 8; ++a) acc[a][e] += bv;
    }

    if (kind == 0) {
        // unary: sum_e relu(e)*wr  (+ br)
        float wvv[8];
        #pragma unroll
        for (int e = 0; e < 8; ++e) wvv[e] = wr[uu*DD + et*8+e];
        #pragma unroll
        for (int a = 0; a < 8; ++a) {
            float s = 0.f;
            #pragma unroll
            for (int e = 0; e < 8; ++e) s = fmaf(fmaxf(acc[a][e], 0.f), wvv[e], s);
            Us[tt*8+a][et] = s;     // partial[token][et]
        }
        __syncthreads();
        const int token = tid >> 2, q = tid & 3;
        float s2 = 0.f;
        #pragma unroll
        for (int z = 0; z < 8; ++z) s2 += Us[token][q*8+z];
        s2 += __shfl_xor(s2, 1, 4);
        s2 += __shfl_xor(s2, 2, 4);
        if (q == 0) ws[OFF_UNARY + uu*MM + row0 + token] = s2 + br[uu];
        return;
    }

    // norm tasks: per-token sum of squares
    #pragma unroll
    for (int a = 0; a < 8; ++a) {
        float s = 0.f;
        #pragma unroll
        for (int e = 0; e < 8; ++e) s = fmaf(acc[a][e], acc[a][e], s);
        Us[tt*8+a][et] = s;
    }
    __syncthreads();
    float* normsl = &Wt[0][0];      // 64 inv values (Wt no longer needed)
    {
        const int token = tid >> 2, q = tid & 3;
        float s2 = 0.f;
        #pragma unroll
        for (int z = 0; z < 8; ++z) s2 += Us[token][q*8+z];
        s2 += __shfl_xor(s2, 1, 4);
        s2 += __shfl_xor(s2, 2, 4);
        if (q == 0) {
            const float inv = 1.f / fmaxf(sqrtf(s2), 1e-12f);
            normsl[token] = inv;
            if (kind == 1)      ws[OFF_INVXS + uu*MM + row0 + token] = inv;
            else if (kind == 3) ws[OFF_INVXP + pp*MM + row0 + token] = inv;
            else if (kind == 4) ws[OFF_INVYP + pp*MM + row0 + token] = inv;
        }
    }
    if (kind == 1) return;

    __syncthreads();
    float inv8[8];
    #pragma unroll
    for (int a = 0; a < 8; ++a) inv8[a] = normsl[tt*8+a];
    float pv[8];
    #pragma unroll
    for (int e = 0; e < 8; ++e) {
        float s = 0.f;
        #pragma unroll
        for (int a = 0; a < 8; ++a) s = fmaf(acc[a][e], inv8[a], s);
        pv[e] = s;
    }
    float* redl = &Us[0][0];        // 256 accumulation slots (Us partials consumed)
    redl[tid] = 0.f;
    __syncthreads();
    #pragma unroll
    for (int e = 0; e < 8; ++e) atomicAdd(&redl[et*8+e], pv[e]);
    __syncthreads();
    float* bar = (kind == 2) ? ws + OFF_YBAR  + ((size_t)uu*BB + b)*DD
               : (kind == 3) ? ws + OFF_XPBAR + ((size_t)pp*BB + b)*DD
                             : ws + OFF_YPBAR + ((size_t)pp*BB + b)*DD;
    atomicAdd(&bar[tid], redl[tid]);
}

// ---------------------------------------------------------------------------
// Pass 2a: proj[d] = sum_e W[e][d] * (bar[e]/N);  cs = sum_e bias[e]*(bar[e]/N)
// 15 tasks x 16 batches. pot_x uses (Wpx, Ypbar); pot_y uses (Wpy, Xpbar).
// ---------------------------------------------------------------------------
__global__ __launch_bounds__(256) void proj_kernel(
    const float* __restrict__ Wsx, const float* __restrict__ bsx,
    const float* __restrict__ Wpx, const float* __restrict__ bpx,
    const float* __restrict__ Wpy, const float* __restrict__ bpy,
    float* __restrict__ ws)
{
    __shared__ float barl[DD];
    __shared__ float redl[256];
    const int task = blockIdx.x >> 4;
    const int b    = blockIdx.x & 15;
    const int tid  = threadIdx.x;
    const float *W, *bias, *barp;
    float *projp, *csp;
    if (task < 3) {
        const int u = task;
        W = Wsx + u*DD*DD; bias = bsx + u*DD;
        barp  = ws + OFF_YBAR  + ((size_t)u*BB + b)*DD;
        projp = ws + OFF_PROJS + ((size_t)u*BB + b)*DD;
        csp   = ws + OFF_CSS + u*BB + b;
    } else if (task < 9) {
        const int p = task - 3; const int i = p>>1, j = pair_j_of(i, p&1);
        W = Wpx + (i*NU+j)*DD*DD; bias = bpx + (i*NU+j)*DD;
        barp  = ws + OFF_YPBAR + ((size_t)p*BB + b)*DD;
        projp = ws + OFF_PROJX + ((size_t)p*BB + b)*DD;
        csp   = ws + OFF_CSX + p*BB + b;
    } else {
        const int p = task - 9; const int i = p>>1, j = pair_j_of(i, p&1);
        W = Wpy + (i*NU+j)*DD*DD; bias = bpy + (i*NU+j)*DD;
        barp  = ws + OFF_XPBAR + ((size_t)p*BB + b)*DD;
        projp = ws + OFF_PROJY + ((size_t)p*BB + b)*DD;
        csp   = ws + OFF_CSY + p*BB + b;
    }
    barl[tid] = barp[tid] * (1.f / NN);
    __syncthreads();
    float s = 0.f;
    for (int e = 0; e < DD; ++e) s = fmaf(W[(size_t)e*DD + tid], barl[e], s);
    projp[tid] = s;
    redl[tid] = bias[tid] * barl[tid];
    __syncthreads();
    for (int st = 128; st > 0; st >>= 1) {
        if (tid < st) redl[tid] += redl[tid + st];
        __syncthreads();
    }
    if (tid == 0) *csp = redl[0];
}

// ---------------------------------------------------------------------------
// Pass 2b: per-token potentials: pot = (U_row . proj + cs) * inv_norm
// 15 tasks x 512 tiles of 32 tokens. 8 threads per token over D=256.
// ---------------------------------------------------------------------------
__global__ __launch_bounds__(256) void pots_kernel(
    const float* __restrict__ u0, const float* __restrict__ u1, const float* __restrict__ u2,
    float* __restrict__ ws)
{
    __shared__ float projl[DD];
    const int task = blockIdx.y;
    const int row0 = blockIdx.x * 32;
    const int b    = row0 >> 10;
    const int tid  = threadIdx.x;
    const float *src, *projp, *invp, *csp;
    float *outp;
    if (task < 3) {
        const int u = task;
        src = selU(u,u0,u1,u2);
        projp = ws + OFF_PROJS + ((size_t)u*BB + b)*DD;
        csp   = ws + OFF_CSS + u*BB + b;
        invp  = ws + OFF_INVXS + (size_t)u*MM;
        outp  = ws + OFF_SELFP + (size_t)u*MM;
    } else if (task < 9) {
        const int p = task - 3; const int i = p>>1, j = pair_j_of(i,p&1);
        src = selU(i,u0,u1,u2);
        projp = ws + OFF_PROJX + ((size_t)p*BB + b)*DD;
        csp   = ws + OFF_CSX + p*BB + b;
        invp  = ws + OFF_INVXP + (size_t)p*MM;
        outp  = ws + OFF_POTX + (size_t)p*MM;
    } else {
        const int p = task - 9; const int i = p>>1, j = pair_j_of(i,p&1);
        src = selU(j,u0,u1,u2);
        projp = ws + OFF_PROJY + ((size_t)p*BB + b)*DD;
        csp   = ws + OFF_CSY + p*BB + b;
        invp  = ws + OFF_INVYP + (size_t)p*MM;
        outp  = ws + OFF_POTY + (size_t)p*MM;
    }
    projl[tid] = projp[tid];
    __syncthreads();
    const float csv = *csp;
    const int token = tid >> 3, q = tid & 7;
    const int row = row0 + token;
    float s = 0.f;
    #pragma unroll
    for (int q4 = 0; q4 < 8; ++q4) {
        const int d0 = q*32 + q4*4;
        const float4 v = *reinterpret_cast<const float4*>(src + (size_t)row*DD + d0);
        s = fmaf(v.x, projl[d0+0], s);
        s = fmaf(v.y, projl[d0+1], s);
        s = fmaf(v.z, projl[d0+2], s);
        s = fmaf(v.w, projl[d0+3], s);
    }
    s += __shfl_xor(s, 1, 8);
    s += __shfl_xor(s, 2, 8);
    s += __shfl_xor(s, 4, 8);
    if (q == 0) outp[row] = (s + csv) * invp[row];
}

// ---------------------------------------------------------------------------
// Pass 3: per (i,j,b): logits -> softmax over n -> attended feature (D)
// ---------------------------------------------------------------------------
__global__ __launch_bounds__(256) void attend_kernel(
    const float* __restrict__ u0, const float* __restrict__ u1, const float* __restrict__ u2,
    const float* __restrict__ wdiag, const float* __restrict__ wpair,
    const float* __restrict__ ws, float* __restrict__ out)
{
    __shared__ float logit[NN];
    __shared__ float redl[256];
    const int c = blockIdx.x;
    const int b = c & 15;
    const int ij = c >> 4;
    const int i = ij / 3, j = ij % 3;
    const int tid = threadIdx.x;

    if (i == j) {
        const int k1 = (i == 0) ? 1 : 0;
        const int k2 = (i == 2) ? 1 : 2;
        const int p1 = i*2 + (k1 > i ? k1-1 : k1);
        const int p2 = i*2 + (k2 > i ? k2-1 : k2);
        const float w0 = wdiag[i*4+0], w1 = wdiag[i*4+1], w2 = wdiag[i*4+2], w3 = wdiag[i*4+3];
        for (int n = tid; n < NN; n += 256) {
            const int row = b*NN + n;
            logit[n] = w0*ws[OFF_UNARY + i*MM + row] + w1*ws[OFF_SELFP + i*MM + row]
                     + w2*ws[OFF_POTX + p1*MM + row] + w3*ws[OFF_POTX + p2*MM + row];
        }
    } else {
        const int p = i*2 + (j > i ? j-1 : j);
        const float w0 = wpair[(i*3+j)*3+0], w1 = wpair[(i*3+j)*3+1], w2 = wpair[(i*3+j)*3+2];
        for (int n = tid; n < NN; n += 256) {
            const int row = b*NN + n;
            logit[n] = w0*ws[OFF_UNARY + j*MM + row] + w1*ws[OFF_SELFP + j*MM + row]
                     + w2*ws[OFF_POTY + p*MM + row];
        }
    }
    __syncthreads();
    float m = -1e30f;
    for (int n = tid; n < NN; n += 256) m = fmaxf(m, logit[n]);
    redl[tid] = m; __syncthreads();
    for (int st = 128; st > 0; st >>= 1) {
        if (tid < st) redl[tid] = fmaxf(redl[tid], redl[tid+st]);
        __syncthreads();
    }
    m = redl[0];
    __syncthreads();
    float ssum = 0.f;
    for (int n = tid; n < NN; n += 256) {
        const float e = expf(logit[n] - m);
        logit[n] = e;
        ssum += e;
    }
    redl[tid] = ssum; __syncthreads();
    for (int st = 128; st > 0; st >>= 1) {
        if (tid < st) redl[tid] += redl[tid+st];
        __syncthreads();
    }
    const float invS = 1.f / redl[0];

    const float* Uj = selU(j, u0, u1, u2);
    float acc = 0.f;
    #pragma unroll 8
    for (int n = 0; n < NN; ++n) {
        acc = fmaf(logit[n], Uj[((size_t)b*NN + n)*DD + tid], acc);
    }
    out[(((size_t)i*3 + j)*BB + b)*DD + tid] = acc * invS;
}

// ---------------------------------------------------------------------------
extern "C" void kernel_launch(void* const* d_in, const int* in_sizes, int n_in,
                              void* d_out, int out_size, void* d_ws, size_t ws_size,
                              hipStream_t stream)
{
    (void)in_sizes; (void)n_in; (void)out_size; (void)ws_size;
    const float* u0    = (const float*)d_in[0];
    const float* u1    = (const float*)d_in[1];
    const float* u2    = (const float*)d_in[2];
    const float* Wu    = (const float*)d_in[3];
    const float* bu    = (const float*)d_in[4];
    const float* wr    = (const float*)d_in[5];
    const float* br    = (const float*)d_in[6];
    const float* Wsx   = (const float*)d_in[7];
    const float* bsx   = (const float*)d_in[8];
    const float* Wsy   = (const float*)d_in[9];
    const float* bsy   = (const float*)d_in[10];
    const float* Wpx   = (const float*)d_in[11];
    const float* bpx   = (const float*)d_in[12];
    const float* Wpy   = (const float*)d_in[13];
    const float* bpy   = (const float*)d_in[14];
    const float* wdiag = (const float*)d_in[15];
    const float* wpair = (const float*)d_in[16];
    float* ws  = (float*)d_ws;
    float* out = (float*)d_out;

    // zero the atomic accumulators (Ybar, Xpbar, Ypbar are contiguous)
    hipMemsetAsync(ws + OFF_YBAR, 0, (size_t)(NU + 2*NPAIR)*BB*DD*sizeof(float), stream);

    dim3 g1(MM/64, 21);
    pass1_kernel<<<g1, 256, 0, stream>>>(u0,u1,u2,Wu,bu,wr,br,Wsx,bsx,Wsy,bsy,Wpx,bpx,Wpy,bpy,ws);
    proj_kernel<<<15*BB, 256, 0, stream>>>(Wsx,bsx,Wpx,bpx,Wpy,bpy,ws);
    dim3 g2(MM/32, 15);
    pots_kernel<<<g2, 256, 0, stream>>>(u0,u1,u2,ws);
    attend_kernel<<<9*BB, 256, 0, stream>>>(u0,u1,u2,wdiag,wpair,ws,out);
}

// Round 2
// 170.930 us; speedup vs baseline: 3.9508x; 3.9508x over previous
//
#include <hip/hip_runtime.h>
#include <math.h>

#define NU 3
#define BB 16
#define NN 1024
#define DD 256
#define MM (BB*NN)      // 16384 tokens per util
#define NPAIR 6

// workspace layout (float element offsets)
#define OFF_UNARY  0
#define OFF_INVXS  (OFF_UNARY + NU*MM)
#define OFF_INVXP  (OFF_INVXS + NU*MM)
#define OFF_INVYP  (OFF_INVXP + NPAIR*MM)
#define OFF_YBAR   (OFF_INVYP + NPAIR*MM)          // bars contiguous for one memset
#define OFF_XPBAR  (OFF_YBAR + NU*BB*DD)
#define OFF_YPBAR  (OFF_XPBAR + NPAIR*BB*DD)
#define OFF_PROJS  (OFF_YPBAR + NPAIR*BB*DD)
#define OFF_PROJX  (OFF_PROJS + NU*BB*DD)
#define OFF_PROJY  (OFF_PROJX + NPAIR*BB*DD)
#define OFF_CSS    (OFF_PROJY + NPAIR*BB*DD)
#define OFF_CSX    (OFF_CSS + NU*BB)
#define OFF_CSY    (OFF_CSX + NPAIR*BB)
#define OFF_SELFP  (OFF_CSY + NPAIR*BB)
#define OFF_POTX   (OFF_SELFP + NU*MM)
#define OFF_POTY   (OFF_POTX + NPAIR*MM)
#define WS_FLOATS  (OFF_POTY + NPAIR*MM)
// f16 weights live after WS_FLOATS: 21 tasks x 65536 halves (pre-swizzled granules)

typedef _Float16 half8 __attribute__((ext_vector_type(8)));
typedef float f32x4 __attribute__((ext_vector_type(4)));

__device__ __forceinline__ int pair_j_of(int i, int idx) {
    return idx == 0 ? (i == 0 ? 1 : 0) : (i == 2 ? 1 : 2);
}
__device__ __forceinline__ const float* selU(int u, const float* u0, const float* u1, const float* u2) {
    return u == 0 ? u0 : (u == 1 ? u1 : u2);
}
__device__ __forceinline__ half8 cvt8(float4 a, float4 b) {
    half8 h = { (_Float16)a.x,(_Float16)a.y,(_Float16)a.z,(_Float16)a.w,
                (_Float16)b.x,(_Float16)b.y,(_Float16)b.z,(_Float16)b.w };
    return h;
}

// ---------------------------------------------------------------------------
// Weight convert: fp32 -> f16, per-task layout [kc=8][granule G=0..1023] where
// granule G holds row e=G>>2, k-granule kg=(G&3)^((e>>1)&3) (XOR swizzle baked
// in so pass1 can copy linearly into LDS and ds_read conflict-free).
// ---------------------------------------------------------------------------
__global__ __launch_bounds__(256) void convw_kernel(
    const float* __restrict__ Wu, const float* __restrict__ Wsx, const float* __restrict__ Wsy,
    const float* __restrict__ Wpx, const float* __restrict__ Wpy, float* __restrict__ ws)
{
    const int task = blockIdx.x;
    const int kc   = blockIdx.y;
    const int tid  = threadIdx.x;
    const float* W;
    if (task < 3)       W = Wu  + (size_t)task*DD*DD;
    else if (task < 6)  W = Wsx + (size_t)(task-3)*DD*DD;
    else if (task < 9)  W = Wsy + (size_t)(task-6)*DD*DD;
    else if (task < 15) { const int p = task-9;  const int i = p>>1, j = pair_j_of(i,p&1);
                          W = Wpx + (size_t)(i*NU+j)*DD*DD; }
    else                { const int p = task-15; const int i = p>>1, j = pair_j_of(i,p&1);
                          W = Wpy + (size_t)(i*NU+j)*DD*DD; }
    _Float16* wh = (_Float16*)(ws + WS_FLOATS) + (size_t)task*65536 + kc*8192;
    #pragma unroll
    for (int g = 0; g < 4; ++g) {
        const int G  = g*256 + tid;
        const int e  = G >> 2;
        const int kg = (G & 3) ^ ((e >> 1) & 3);
        const float* s = W + (size_t)e*DD + kc*32 + kg*8;
        const float4 v0 = *reinterpret_cast<const float4*>(s);
        const float4 v1 = *reinterpret_cast<const float4*>(s + 4);
        *reinterpret_cast<half8*>(wh + (size_t)G*8) = cvt8(v0, v1);
    }
}

// ---------------------------------------------------------------------------
// Pass 1 (MFMA): 21 tasks x 128-token tiles. Block = 4 waves (2 token-halves x
// 2 e-halves); wave tile = 64 tokens x 128 e via mfma_f32_16x16x32_f16.
// Fused epilogues as in round 1.
// ---------------------------------------------------------------------------
__global__ __launch_bounds__(256, 2) void pass1_kernel(
    const float* __restrict__ u0, const float* __restrict__ u1, const float* __restrict__ u2,
    const float* __restrict__ bu, const float* __restrict__ wr, const float* __restrict__ br,
    const float* __restrict__ bsx, const float* __restrict__ bsy,
    const float* __restrict__ bpx, const float* __restrict__ bpy,
    float* __restrict__ ws)
{
    __shared__ __align__(16) _Float16 Wb[2][8192];   // 2 x 256e x 32k
    __shared__ __align__(16) _Float16 Ub[2][4096];   // 2 x 128tok x 32k
    __shared__ float ep_sum[2][128];
    __shared__ float ep_inv[128];
    __shared__ float ep_bar[256];

    const int tid  = threadIdx.x;
    const int task = blockIdx.y;
    const int row0 = blockIdx.x * 128;
    const int b    = row0 >> 10;

    int kind, uu = 0, pp = 0;
    const float *bias, *src;
    if (task < 3)       { kind=0; uu=task;    bias=bu +uu*DD; src=selU(uu,u0,u1,u2); }
    else if (task < 6)  { kind=1; uu=task-3;  bias=bsx+uu*DD; src=selU(uu,u0,u1,u2); }
    else if (task < 9)  { kind=2; uu=task-6;  bias=bsy+uu*DD; src=selU(uu,u0,u1,u2); }
    else if (task < 15) { kind=3; pp=task-9;  const int i=pp>>1, j=pair_j_of(i,pp&1);
                          bias=bpx+(i*NU+j)*DD; src=selU(i,u0,u1,u2); }
    else                { kind=4; pp=task-15; const int i=pp>>1, j=pair_j_of(i,pp&1);
                          bias=bpy+(i*NU+j)*DD; src=selU(j,u0,u1,u2); }
    const _Float16* wh = (const _Float16*)(ws + WS_FLOATS) + (size_t)task*65536;

    const int lane = tid & 63, wave = tid >> 6;
    const int l15 = lane & 15, lg = lane >> 4;
    const int wtok = (wave >> 1) * 64;      // token half
    const int ebase = (wave & 1) * 128;     // e half
    const int swz = (l15 >> 1) & 3;

    // U staging: this thread owns granules G0, G1 of the 128x32 tile
    const int G0 = tid, G1 = tid + 256;
    const int t0 = G0 >> 2, t1 = G1 >> 2;
    const int kg0 = (G0 & 3) ^ ((t0 >> 1) & 3);
    const int kg1 = (G1 & 3) ^ ((t1 >> 1) & 3);
    const float* us0 = src + (size_t)(row0 + t0)*DD + kg0*8;
    const float* us1 = src + (size_t)(row0 + t1)*DD + kg1*8;

    f32x4 acc[4][8];
    #pragma unroll
    for (int m = 0; m < 4; ++m)
        #pragma unroll
        for (int n = 0; n < 8; ++n) acc[m][n] = (f32x4)0.f;

    // prologue: stage kc=0
    #pragma unroll
    for (int g = 0; g < 4; ++g) {
        const int G = g*256 + tid;
        *reinterpret_cast<half8*>(&Wb[0][G*8]) = *reinterpret_cast<const half8*>(wh + G*8);
    }
    {
        const float4 a0 = *reinterpret_cast<const float4*>(us0);
        const float4 a1 = *reinterpret_cast<const float4*>(us0 + 4);
        const float4 b0 = *reinterpret_cast<const float4*>(us1);
        const float4 b1 = *reinterpret_cast<const float4*>(us1 + 4);
        *reinterpret_cast<half8*>(&Ub[0][G0*8]) = cvt8(a0, a1);
        *reinterpret_cast<half8*>(&Ub[0][G1*8]) = cvt8(b0, b1);
    }
    __syncthreads();

    const int abase = (wtok + l15)*32 + (lg ^ swz)*8;
    const int bbase = (ebase + l15)*32 + (lg ^ swz)*8;

    for (int kc = 0; kc < 8; ++kc) {
        const int cur = kc & 1;
        half8 wreg[4];
        float4 ua[4];
        if (kc < 7) {   // issue next-tile global loads early (latency hides under MFMA)
            const _Float16* whk = wh + (size_t)(kc+1)*8192;
            #pragma unroll
            for (int g = 0; g < 4; ++g)
                wreg[g] = *reinterpret_cast<const half8*>(whk + (size_t)(g*256 + tid)*8);
            const float* p0 = us0 + (kc+1)*32;
            const float* p1 = us1 + (kc+1)*32;
            ua[0] = *reinterpret_cast<const float4*>(p0);
            ua[1] = *reinterpret_cast<const float4*>(p0 + 4);
            ua[2] = *reinterpret_cast<const float4*>(p1);
            ua[3] = *reinterpret_cast<const float4*>(p1 + 4);
        }
        // compute on current buffers
        half8 af[4];
        #pragma unroll
        for (int m = 0; m < 4; ++m)
            af[m] = *reinterpret_cast<const half8*>(&Ub[cur][abase + m*512]);
        #pragma unroll
        for (int n = 0; n < 8; ++n) {
            const half8 bf = *reinterpret_cast<const half8*>(&Wb[cur][bbase + n*512]);
            #pragma unroll
            for (int m = 0; m < 4; ++m)
                acc[m][n] = __builtin_amdgcn_mfma_f32_16x16x32_f16(af[m], bf, acc[m][n], 0, 0, 0);
        }
        if (kc < 7) {   // write next tile
            const int nxt = cur ^ 1;
            #pragma unroll
            for (int g = 0; g < 4; ++g)
                *reinterpret_cast<half8*>(&Wb[nxt][(g*256 + tid)*8]) = wreg[g];
            *reinterpret_cast<half8*>(&Ub[nxt][G0*8]) = cvt8(ua[0], ua[1]);
            *reinterpret_cast<half8*>(&Ub[nxt][G1*8]) = cvt8(ua[2], ua[3]);
        }
        __syncthreads();
    }

    // ---- epilogue ----
    // bias add (bias depends on e only)
    float bv[8];
    #pragma unroll
    for (int n = 0; n < 8; ++n) bv[n] = bias[ebase + n*16 + l15];
    #pragma unroll
    for (int m = 0; m < 4; ++m)
        #pragma unroll
        for (int n = 0; n < 8; ++n)
            #pragma unroll
            for (int r = 0; r < 4; ++r) acc[m][n][r] += bv[n];

    const int we = wave & 1;

    if (kind == 0) {
        float wrv[8];
        #pragma unroll
        for (int n = 0; n < 8; ++n) wrv[n] = wr[uu*DD + ebase + n*16 + l15];
        float p[4][4];
        #pragma unroll
        for (int m = 0; m < 4; ++m)
            #pragma unroll
            for (int r = 0; r < 4; ++r) {
                float s = 0.f;
                #pragma unroll
                for (int n = 0; n < 8; ++n) s = fmaf(fmaxf(acc[m][n][r], 0.f), wrv[n], s);
                p[m][r] = s;
            }
        #pragma unroll
        for (int mask = 1; mask <= 8; mask <<= 1)
            #pragma unroll
            for (int m = 0; m < 4; ++m)
                #pragma unroll
                for (int r = 0; r < 4; ++r) p[m][r] += __shfl_xor(p[m][r], mask);
        if (l15 == 0) {
            #pragma unroll
            for (int m = 0; m < 4; ++m)
                #pragma unroll
                for (int r = 0; r < 4; ++r) ep_sum[we][wtok + m*16 + lg*4 + r] = p[m][r];
        }
        __syncthreads();
        if (tid < 128)
            ws[OFF_UNARY + (size_t)uu*MM + row0 + tid] = ep_sum[0][tid] + ep_sum[1][tid] + br[uu];
        return;
    }

    // norm kinds: per-token sum of squares
    {
        float p[4][4];
        #pragma unroll
        for (int m = 0; m < 4; ++m)
            #pragma unroll
            for (int r = 0; r < 4; ++r) {
                float s = 0.f;
                #pragma unroll
                for (int n = 0; n < 8; ++n) s = fmaf(acc[m][n][r], acc[m][n][r], s);
                p[m][r] = s;
            }
        #pragma unroll
        for (int mask = 1; mask <= 8; mask <<= 1)
            #pragma unroll
            for (int m = 0; m < 4; ++m)
                #pragma unroll
                for (int r = 0; r < 4; ++r) p[m][r] += __shfl_xor(p[m][r], mask);
        if (l15 == 0) {
            #pragma unroll
            for (int m = 0; m < 4; ++m)
                #pragma unroll
                for (int r = 0; r < 4; ++r) ep_sum[we][wtok + m*16 + lg*4 + r] = p[m][r];
        }
    }
    ep_bar[tid] = 0.f;
    __syncthreads();
    if (tid < 128) {
        const float ssum = ep_sum[0][tid] + ep_sum[1][tid];
        const float inv = 1.f / fmaxf(sqrtf(ssum), 1e-12f);
        ep_inv[tid] = inv;
        if (kind == 1)      ws[OFF_INVXS + (size_t)uu*MM + row0 + tid] = inv;
        else if (kind == 3) ws[OFF_INVXP + (size_t)pp*MM + row0 + tid] = inv;
        else if (kind == 4) ws[OFF_INVYP + (size_t)pp*MM + row0 + tid] = inv;
    }
    __syncthreads();
    if (kind == 1) return;

    float invv[4][4];
    #pragma unroll
    for (int m = 0; m < 4; ++m)
        #pragma unroll
        for (int r = 0; r < 4; ++r) invv[m][r] = ep_inv[wtok + m*16 + lg*4 + r];
    float q[8];
    #pragma unroll
    for (int n = 0; n < 8; ++n) {
        float s = 0.f;
        #pragma unroll
        for (int m = 0; m < 4; ++m)
            #pragma unroll
            for (int r = 0; r < 4; ++r) s = fmaf(acc[m][n][r], invv[m][r], s);
        q[n] = s;
    }
    #pragma unroll
    for (int n = 0; n < 8; ++n) {
        q[n] += __shfl_xor(q[n], 16);
        q[n] += __shfl_xor(q[n], 32);
    }
    if (lane < 16) {
        #pragma unroll
        for (int n = 0; n < 8; ++n) atomicAdd(&ep_bar[ebase + n*16 + lane], q[n]);
    }
    __syncthreads();
    float* bar = (kind == 2) ? ws + OFF_YBAR  + ((size_t)uu*BB + b)*DD
               : (kind == 3) ? ws + OFF_XPBAR + ((size_t)pp*BB + b)*DD
                             : ws + OFF_YPBAR + ((size_t)pp*BB + b)*DD;
    atomicAdd(&bar[tid], ep_bar[tid]);
}

// ---------------------------------------------------------------------------
// Pass 2a: proj[d] = sum_e W[e][d] * (bar[e]/N);  cs = sum_e bias[e]*(bar[e]/N)
// ---------------------------------------------------------------------------
__global__ __launch_bounds__(256) void proj_kernel(
    const float* __restrict__ Wsx, const float* __restrict__ bsx,
    const float* __restrict__ Wpx, const float* __restrict__ bpx,
    const float* __restrict__ Wpy, const float* __restrict__ bpy,
    float* __restrict__ ws)
{
    __shared__ float barl[DD];
    __shared__ float redl[256];
    const int task = blockIdx.x >> 4;
    const int b    = blockIdx.x & 15;
    const int tid  = threadIdx.x;
    const float *W, *bias, *barp;
    float *projp, *csp;
    if (task < 3) {
        const int u = task;
        W = Wsx + (size_t)u*DD*DD; bias = bsx + u*DD;
        barp  = ws + OFF_YBAR  + ((size_t)u*BB + b)*DD;
        projp = ws + OFF_PROJS + ((size_t)u*BB + b)*DD;
        csp   = ws + OFF_CSS + u*BB + b;
    } else if (task < 9) {
        const int p = task - 3; const int i = p>>1, j = pair_j_of(i, p&1);
        W = Wpx + (size_t)(i*NU+j)*DD*DD; bias = bpx + (i*NU+j)*DD;
        barp  = ws + OFF_YPBAR + ((size_t)p*BB + b)*DD;
        projp = ws + OFF_PROJX + ((size_t)p*BB + b)*DD;
        csp   = ws + OFF_CSX + p*BB + b;
    } else {
        const int p = task - 9; const int i = p>>1, j = pair_j_of(i, p&1);
        W = Wpy + (size_t)(i*NU+j)*DD*DD; bias = bpy + (i*NU+j)*DD;
        barp  = ws + OFF_XPBAR + ((size_t)p*BB + b)*DD;
        projp = ws + OFF_PROJY + ((size_t)p*BB + b)*DD;
        csp   = ws + OFF_CSY + p*BB + b;
    }
    barl[tid] = barp[tid] * (1.f / NN);
    __syncthreads();
    float s = 0.f;
    for (int e = 0; e < DD; ++e) s = fmaf(W[(size_t)e*DD + tid], barl[e], s);
    projp[tid] = s;
    redl[tid] = bias[tid] * barl[tid];
    __syncthreads();
    for (int st = 128; st > 0; st >>= 1) {
        if (tid < st) redl[tid] += redl[tid + st];
        __syncthreads();
    }
    if (tid == 0) *csp = redl[0];
}

// ---------------------------------------------------------------------------
// Pass 2b: per-token potentials: pot = (U_row . proj + cs) * inv_norm
// ---------------------------------------------------------------------------
__global__ __launch_bounds__(256) void pots_kernel(
    const float* __restrict__ u0, const float* __restrict__ u1, const float* __restrict__ u2,
    float* __restrict__ ws)
{
    __shared__ float projl[DD];
    const int task = blockIdx.y;
    const int row0 = blockIdx.x * 32;
    const int b    = row0 >> 10;
    const int tid  = threadIdx.x;
    const float *src, *projp, *invp, *csp;
    float *outp;
    if (task < 3) {
        const int u = task;
        src = selU(u,u0,u1,u2);
        projp = ws + OFF_PROJS + ((size_t)u*BB + b)*DD;
        csp   = ws + OFF_CSS + u*BB + b;
        invp  = ws + OFF_INVXS + (size_t)u*MM;
        outp  = ws + OFF_SELFP + (size_t)u*MM;
    } else if (task < 9) {
        const int p = task - 3; const int i = p>>1, j = pair_j_of(i,p&1);
        src = selU(i,u0,u1,u2);
        projp = ws + OFF_PROJX + ((size_t)p*BB + b)*DD;
        csp   = ws + OFF_CSX + p*BB + b;
        invp  = ws + OFF_INVXP + (size_t)p*MM;
        outp  = ws + OFF_POTX + (size_t)p*MM;
    } else {
        const int p = task - 9; const int i = p>>1, j = pair_j_of(i,p&1);
        src = selU(j,u0,u1,u2);
        projp = ws + OFF_PROJY + ((size_t)p*BB + b)*DD;
        csp   = ws + OFF_CSY + p*BB + b;
        invp  = ws + OFF_INVYP + (size_t)p*MM;
        outp  = ws + OFF_POTY + (size_t)p*MM;
    }
    projl[tid] = projp[tid];
    __syncthreads();
    const float csv = *csp;
    const int token = tid >> 3, q = tid & 7;
    const int row = row0 + token;
    float s = 0.f;
    #pragma unroll
    for (int q4 = 0; q4 < 8; ++q4) {
        const int d0 = q*32 + q4*4;
        const float4 v = *reinterpret_cast<const float4*>(src + (size_t)row*DD + d0);
        s = fmaf(v.x, projl[d0+0], s);
        s = fmaf(v.y, projl[d0+1], s);
        s = fmaf(v.z, projl[d0+2], s);
        s = fmaf(v.w, projl[d0+3], s);
    }
    s += __shfl_xor(s, 1, 8);
    s += __shfl_xor(s, 2, 8);
    s += __shfl_xor(s, 4, 8);
    if (q == 0) outp[row] = (s + csv) * invp[row];
}

// ---------------------------------------------------------------------------
// Pass 3: per (i,j,b): logits -> softmax over n -> attended feature (D)
// ---------------------------------------------------------------------------
__global__ __launch_bounds__(256) void attend_kernel(
    const float* __restrict__ u0, const float* __restrict__ u1, const float* __restrict__ u2,
    const float* __restrict__ wdiag, const float* __restrict__ wpair,
    const float* __restrict__ ws, float* __restrict__ out)
{
    __shared__ float logit[NN];
    __shared__ float redl[256];
    const int c = blockIdx.x;
    const int b = c & 15;
    const int ij = c >> 4;
    const int i = ij / 3, j = ij % 3;
    const int tid = threadIdx.x;

    if (i == j) {
        const int k1 = (i == 0) ? 1 : 0;
        const int k2 = (i == 2) ? 1 : 2;
        const int p1 = i*2 + (k1 > i ? k1-1 : k1);
        const int p2 = i*2 + (k2 > i ? k2-1 : k2);
        const float w0 = wdiag[i*4+0], w1 = wdiag[i*4+1], w2 = wdiag[i*4+2], w3 = wdiag[i*4+3];
        for (int n = tid; n < NN; n += 256) {
            const int row = b*NN + n;
            logit[n] = w0*ws[OFF_UNARY + i*MM + row] + w1*ws[OFF_SELFP + i*MM + row]
                     + w2*ws[OFF_POTX + p1*MM + row] + w3*ws[OFF_POTX + p2*MM + row];
        }
    } else {
        const int p = i*2 + (j > i ? j-1 : j);
        const float w0 = wpair[(i*3+j)*3+0], w1 = wpair[(i*3+j)*3+1], w2 = wpair[(i*3+j)*3+2];
        for (int n = tid; n < NN; n += 256) {
            const int row = b*NN + n;
            logit[n] = w0*ws[OFF_UNARY + j*MM + row] + w1*ws[OFF_SELFP + j*MM + row]
                     + w2*ws[OFF_POTY + p*MM + row];
        }
    }
    __syncthreads();
    float m = -1e30f;
    for (int n = tid; n < NN; n += 256) m = fmaxf(m, logit[n]);
    redl[tid] = m; __syncthreads();
    for (int st = 128; st > 0; st >>= 1) {
        if (tid < st) redl[tid] = fmaxf(redl[tid], redl[tid+st]);
        __syncthreads();
    }
    m = redl[0];
    __syncthreads();
    float ssum = 0.f;
    for (int n = tid; n < NN; n += 256) {
        const float e = expf(logit[n] - m);
        logit[n] = e;
        ssum += e;
    }
    redl[tid] = ssum; __syncthreads();
    for (int st = 128; st > 0; st >>= 1) {
        if (tid < st) redl[tid] += redl[tid+st];
        __syncthreads();
    }
    const float invS = 1.f / redl[0];

    const float* Uj = selU(j, u0, u1, u2);
    float acc = 0.f;
    #pragma unroll 8
    for (int n = 0; n < NN; ++n) {
        acc = fmaf(logit[n], Uj[((size_t)b*NN + n)*DD + tid], acc);
    }
    out[(((size_t)i*3 + j)*BB + b)*DD + tid] = acc * invS;
}

// ---------------------------------------------------------------------------
extern "C" void kernel_launch(void* const* d_in, const int* in_sizes, int n_in,
                              void* d_out, int out_size, void* d_ws, size_t ws_size,
                              hipStream_t stream)
{
    (void)in_sizes; (void)n_in; (void)out_size; (void)ws_size;
    const float* u0    = (const float*)d_in[0];
    const float* u1    = (const float*)d_in[1];
    const float* u2    = (const float*)d_in[2];
    const float* Wu    = (const float*)d_in[3];
    const float* bu    = (const float*)d_in[4];
    const float* wr    = (const float*)d_in[5];
    const float* br    = (const float*)d_in[6];
    const float* Wsx   = (const float*)d_in[7];
    const float* bsx   = (const float*)d_in[8];
    const float* Wsy   = (const float*)d_in[9];
    const float* bsy   = (const float*)d_in[10];
    const float* Wpx   = (const float*)d_in[11];
    const float* bpx   = (const float*)d_in[12];
    const float* Wpy   = (const float*)d_in[13];
    const float* bpy   = (const float*)d_in[14];
    const float* wdiag = (const float*)d_in[15];
    const float* wpair = (const float*)d_in[16];
    float* ws  = (float*)d_ws;
    float* out = (float*)d_out;

    // zero the atomic accumulators (Ybar, Xpbar, Ypbar are contiguous)
    hipMemsetAsync(ws + OFF_YBAR, 0, (size_t)(NU + 2*NPAIR)*BB*DD*sizeof(float), stream);

    dim3 gw(21, 8);
    convw_kernel<<<gw, 256, 0, stream>>>(Wu, Wsx, Wsy, Wpx, Wpy, ws);

    dim3 g1(MM/128, 21);
    pass1_kernel<<<g1, 256, 0, stream>>>(u0,u1,u2,bu,wr,br,bsx,bsy,bpx,bpy,ws);

    proj_kernel<<<15*BB, 256, 0, stream>>>(Wsx,bsx,Wpx,bpx,Wpy,bpy,ws);
    dim3 g2(MM/32, 15);
    pots_kernel<<<g2, 256, 0, stream>>>(u0,u1,u2,ws);
    attend_kernel<<<9*BB, 256, 0, stream>>>(u0,u1,u2,wdiag,wpair,ws,out);
}

// Round 3
// 161.993 us; speedup vs baseline: 4.1688x; 1.0552x over previous
//
#include <hip/hip_runtime.h>
#include <math.h>

#define NU 3
#define BB 16
#define NN 1024
#define DD 256
#define MM (BB*NN)      // 16384 tokens per util
#define NPAIR 6

// workspace layout (float element offsets)
#define OFF_UNARY  0
#define OFF_INVXS  (OFF_UNARY + NU*MM)
#define OFF_INVXP  (OFF_INVXS + NU*MM)
#define OFF_INVYP  (OFF_INVXP + NPAIR*MM)
#define OFF_YBAR   (OFF_INVYP + NPAIR*MM)          // bars contiguous for one memset
#define OFF_XPBAR  (OFF_YBAR + NU*BB*DD)
#define OFF_YPBAR  (OFF_XPBAR + NPAIR*BB*DD)
#define OFF_PROJS  (OFF_YPBAR + NPAIR*BB*DD)
#define OFF_PROJX  (OFF_PROJS + NU*BB*DD)
#define OFF_PROJY  (OFF_PROJX + NPAIR*BB*DD)
#define OFF_CSS    (OFF_PROJY + NPAIR*BB*DD)
#define OFF_CSX    (OFF_CSS + NU*BB)
#define OFF_CSY    (OFF_CSX + NPAIR*BB)
#define OFF_SELFP  (OFF_CSY + NPAIR*BB)
#define OFF_POTX   (OFF_SELFP + NU*MM)
#define OFF_POTY   (OFF_POTX + NPAIR*MM)
#define WS_FLOATS  (OFF_POTY + NPAIR*MM)
// f16 weights after WS_FLOATS: 21 slots (u*7+s) x 65536 halves, granule-swizzled

typedef _Float16 half8 __attribute__((ext_vector_type(8)));
typedef float f32x4 __attribute__((ext_vector_type(4)));

__device__ __forceinline__ const float* selU(int u, const float* u0, const float* u1, const float* u2) {
    return u == 0 ? u0 : (u == 1 ? u1 : u2);
}
__device__ __forceinline__ half8 cvt8(float4 a, float4 b) {
    half8 h = { (_Float16)a.x,(_Float16)a.y,(_Float16)a.z,(_Float16)a.w,
                (_Float16)b.x,(_Float16)b.y,(_Float16)b.z,(_Float16)b.w };
    return h;
}

// ---------------------------------------------------------------------------
// Weight convert: fp32 -> f16, slot (u, s=0..6):
// s0 Wu[u]; s1 Wsx[u]; s2 Wsy[u]; s3/s4 Wpx[u->j0/j1]; s5/s6 Wpy[i0/i1->u].
// Layout per slot: [kc=8][granule G=0..1023], G = e*4 + (kg ^ ((e>>1)&3)).
// ---------------------------------------------------------------------------
__global__ __launch_bounds__(256) void convw_kernel(
    const float* __restrict__ Wu, const float* __restrict__ Wsx, const float* __restrict__ Wsy,
    const float* __restrict__ Wpx, const float* __restrict__ Wpy, float* __restrict__ ws)
{
    const int slot = blockIdx.x;          // 0..20
    const int kc   = blockIdx.y;          // 0..7
    const int tid  = threadIdx.x;
    const int u = slot / 7, s = slot % 7;
    const int j0 = (u==0)?1:0, j1 = (u==2)?1:2;   // the two "others", ascending
    const float* W =
        s==0 ? Wu  + (size_t)u*DD*DD :
        s==1 ? Wsx + (size_t)u*DD*DD :
        s==2 ? Wsy + (size_t)u*DD*DD :
        s==3 ? Wpx + (size_t)(u*NU+j0)*DD*DD :
        s==4 ? Wpx + (size_t)(u*NU+j1)*DD*DD :
        s==5 ? Wpy + (size_t)(j0*NU+u)*DD*DD :
               Wpy + (size_t)(j1*NU+u)*DD*DD;
    _Float16* wh = (_Float16*)(ws + WS_FLOATS) + (size_t)slot*65536 + kc*8192;
    #pragma unroll
    for (int g = 0; g < 4; ++g) {
        const int G  = g*256 + tid;
        const int e  = G >> 2;
        const int kg = (G & 3) ^ ((e >> 1) & 3);
        const float* sp = W + (size_t)e*DD + kc*32 + kg*8;
        const float4 v0 = *reinterpret_cast<const float4*>(sp);
        const float4 v1 = *reinterpret_cast<const float4*>(sp + 4);
        *reinterpret_cast<half8*>(wh + (size_t)G*8) = cvt8(v0, v1);
    }
}

__device__ __forceinline__ void mfma_step(const _Float16* __restrict__ Ubp,
    const _Float16* __restrict__ Wbp, int kc, int abase, int bbase, f32x4 acc[4][4])
{
    half8 af[4], bf[4];
    #pragma unroll
    for (int m = 0; m < 4; ++m) af[m] = *reinterpret_cast<const half8*>(Ubp + kc*2048 + abase + m*512);
    #pragma unroll
    for (int n = 0; n < 4; ++n) bf[n] = *reinterpret_cast<const half8*>(Wbp + bbase + n*512);
    #pragma unroll
    for (int n = 0; n < 4; ++n)
        #pragma unroll
        for (int m = 0; m < 4; ++m)
            acc[m][n] = __builtin_amdgcn_mfma_f32_16x16x32_f16(af[m], bf[n], acc[m][n], 0, 0, 0);
}

// ---------------------------------------------------------------------------
// Pass 1 (MFMA, util-fused): grid (MM/64, 3). Block = 64-token tile of util u,
// U tile (64x256 f16) resident in LDS; loops 7 tasks streaming W slabs from
// L2 with 2-deep register prefetch + LDS double-buffer.
// Wave w owns e in [w*64, w*64+64): acc[m][n] -> token m*16+lg*4+r, e w*64+n*16+l15.
// ---------------------------------------------------------------------------
__global__ __launch_bounds__(256, 2) void pass1_kernel(
    const float* __restrict__ u0, const float* __restrict__ u1, const float* __restrict__ u2,
    const float* __restrict__ bu, const float* __restrict__ wr, const float* __restrict__ br,
    const float* __restrict__ bsx, const float* __restrict__ bsy,
    const float* __restrict__ bpx, const float* __restrict__ bpy,
    float* __restrict__ ws)
{
    __shared__ __align__(16) _Float16 Ub[16384];     // 8 slabs x [64 tok x 32 k]
    __shared__ __align__(16) _Float16 Wb[2][8192];   // dbuf x [256 e x 32 k]
    __shared__ float ep_sum[4][64];
    __shared__ float ep_inv[64];

    const int tid  = threadIdx.x;
    const int u    = blockIdx.y;
    const int row0 = blockIdx.x * 64;
    const int b    = row0 >> 10;

    const int j0 = (u==0)?1:0, j1 = (u==2)?1:2;
    const int px0 = u*2, px1 = u*2+1;
    const int py0 = (u==0)?2:((u==1)?0:1);
    const int py1 = (u==0)?4:((u==1)?5:3);

    const float* src = selU(u,u0,u1,u2);
    const _Float16* whU = (const _Float16*)(ws + WS_FLOATS) + (size_t)u*7*65536;

    const int lane = tid & 63, wq = tid >> 6;
    const int l15 = lane & 15, lg = lane >> 4;
    const int swz = (l15 >> 1) & 3;
    const int abase = l15*32 + (lg ^ swz)*8;
    const int bbase = (wq*64 + l15)*32 + (lg ^ swz)*8;

    f32x4 acc[4][4];
    #pragma unroll
    for (int m = 0; m < 4; ++m)
        #pragma unroll
        for (int n = 0; n < 4; ++n) acc[m][n] = (f32x4)0.f;

    half8 RA[4], RB[4];
    // stage slabs it=0,1
    #pragma unroll
    for (int g = 0; g < 4; ++g)
        RA[g] = *reinterpret_cast<const half8*>(whU + (size_t)(g*256 + tid)*8);
    #pragma unroll
    for (int g = 0; g < 4; ++g)
        RB[g] = *reinterpret_cast<const half8*>(whU + 8192 + (size_t)(g*256 + tid)*8);

    // U prologue: 64 tok x 256 k fp32 -> f16 swizzled LDS (once per block)
    #pragma unroll
    for (int c = 0; c < 8; ++c) {
        const int G2 = c*256 + tid;          // 0..2047
        const int t  = G2 >> 5;              // token 0..63
        const int gk = G2 & 31;              // k-granule 0..31
        const int kc = gk >> 2, kg = gk & 3;
        const float* p = src + (size_t)(row0 + t)*DD + gk*8;
        const float4 v0 = *reinterpret_cast<const float4*>(p);
        const float4 v1 = *reinterpret_cast<const float4*>(p + 4);
        const int kgs = kg ^ ((t >> 1) & 3);
        *reinterpret_cast<half8*>(&Ub[kc*2048 + t*32 + kgs*8]) = cvt8(v0, v1);
    }
    #pragma unroll
    for (int g = 0; g < 4; ++g)
        *reinterpret_cast<half8*>(&Wb[0][(g*256 + tid)*8]) = RA[g];
    __syncthreads();

    int task = 0;
    for (int ith = 0; ith < 28; ++ith) {
        const int it0 = 2*ith;
        // ---- even: compute buf0 (slab it0), commit RB->buf1 (slab it0+1), stage RA<-it0+2
        if (it0 + 2 < 56) {
            const _Float16* p = whU + (size_t)(it0+2)*8192;
            #pragma unroll
            for (int g = 0; g < 4; ++g)
                RA[g] = *reinterpret_cast<const half8*>(p + (size_t)(g*256 + tid)*8);
        }
        mfma_step(Ub, &Wb[0][0], it0 & 7, abase, bbase, acc);
        #pragma unroll
        for (int g = 0; g < 4; ++g)
            *reinterpret_cast<half8*>(&Wb[1][(g*256 + tid)*8]) = RB[g];
        __syncthreads();
        // ---- odd: compute buf1 (slab it1), commit RA->buf0 (slab it1+1), stage RB<-it1+2
        const int it1 = it0 + 1;
        if (it1 + 2 < 56) {
            const _Float16* p = whU + (size_t)(it1+2)*8192;
            #pragma unroll
            for (int g = 0; g < 4; ++g)
                RB[g] = *reinterpret_cast<const half8*>(p + (size_t)(g*256 + tid)*8);
        }
        mfma_step(Ub, &Wb[1][0], it1 & 7, abase, bbase, acc);
        if (it1 + 1 < 56) {
            #pragma unroll
            for (int g = 0; g < 4; ++g)
                *reinterpret_cast<half8*>(&Wb[0][(g*256 + tid)*8]) = RA[g];
        }
        __syncthreads();

        if ((it1 & 7) == 7) {
            // ================= epilogue for task s =================
            const int s = task;
            const float* bias =
                s==0 ? bu  + u*DD :
                s==1 ? bsx + u*DD :
                s==2 ? bsy + u*DD :
                s==3 ? bpx + (u*NU+j0)*DD :
                s==4 ? bpx + (u*NU+j1)*DD :
                s==5 ? bpy + (j0*NU+u)*DD :
                       bpy + (j1*NU+u)*DD;
            float bv[4];
            #pragma unroll
            for (int n = 0; n < 4; ++n) bv[n] = bias[wq*64 + n*16 + l15];
            #pragma unroll
            for (int m = 0; m < 4; ++m)
                #pragma unroll
                for (int n = 0; n < 4; ++n)
                    #pragma unroll
                    for (int r = 0; r < 4; ++r) acc[m][n][r] += bv[n];

            if (s == 0) {
                float wrv[4];
                #pragma unroll
                for (int n = 0; n < 4; ++n) wrv[n] = wr[u*DD + wq*64 + n*16 + l15];
                float pm[4][4];
                #pragma unroll
                for (int m = 0; m < 4; ++m)
                    #pragma unroll
                    for (int r = 0; r < 4; ++r) {
                        float t = 0.f;
                        #pragma unroll
                        for (int n = 0; n < 4; ++n) t = fmaf(fmaxf(acc[m][n][r], 0.f), wrv[n], t);
                        pm[m][r] = t;
                    }
                #pragma unroll
                for (int mask = 1; mask <= 8; mask <<= 1)
                    #pragma unroll
                    for (int m = 0; m < 4; ++m)
                        #pragma unroll
                        for (int r = 0; r < 4; ++r) pm[m][r] += __shfl_xor(pm[m][r], mask);
                if (l15 == 0) {
                    #pragma unroll
                    for (int m = 0; m < 4; ++m)
                        #pragma unroll
                        for (int r = 0; r < 4; ++r) ep_sum[wq][m*16 + lg*4 + r] = pm[m][r];
                }
                __syncthreads();
                if (tid < 64)
                    ws[OFF_UNARY + (size_t)u*MM + row0 + tid] =
                        ep_sum[0][tid]+ep_sum[1][tid]+ep_sum[2][tid]+ep_sum[3][tid] + br[u];
            } else {
                float pm[4][4];
                #pragma unroll
                for (int m = 0; m < 4; ++m)
                    #pragma unroll
                    for (int r = 0; r < 4; ++r) {
                        float t = 0.f;
                        #pragma unroll
                        for (int n = 0; n < 4; ++n) t = fmaf(acc[m][n][r], acc[m][n][r], t);
                        pm[m][r] = t;
                    }
                #pragma unroll
                for (int mask = 1; mask <= 8; mask <<= 1)
                    #pragma unroll
                    for (int m = 0; m < 4; ++m)
                        #pragma unroll
                        for (int r = 0; r < 4; ++r) pm[m][r] += __shfl_xor(pm[m][r], mask);
                if (l15 == 0) {
                    #pragma unroll
                    for (int m = 0; m < 4; ++m)
                        #pragma unroll
                        for (int r = 0; r < 4; ++r) ep_sum[wq][m*16 + lg*4 + r] = pm[m][r];
                }
                __syncthreads();
                if (tid < 64) {
                    const float ssum = ep_sum[0][tid]+ep_sum[1][tid]+ep_sum[2][tid]+ep_sum[3][tid];
                    const float inv = 1.f / fmaxf(sqrtf(ssum), 1e-12f);
                    ep_inv[tid] = inv;
                    if (s == 1)      ws[OFF_INVXS + (size_t)u  *MM + row0 + tid] = inv;
                    else if (s == 3) ws[OFF_INVXP + (size_t)px0*MM + row0 + tid] = inv;
                    else if (s == 4) ws[OFF_INVXP + (size_t)px1*MM + row0 + tid] = inv;
                    else if (s == 5) ws[OFF_INVYP + (size_t)py0*MM + row0 + tid] = inv;
                    else if (s == 6) ws[OFF_INVYP + (size_t)py1*MM + row0 + tid] = inv;
                }
                __syncthreads();
                if (s >= 2) {
                    float invv[4][4];
                    #pragma unroll
                    for (int m = 0; m < 4; ++m)
                        #pragma unroll
                        for (int r = 0; r < 4; ++r) invv[m][r] = ep_inv[m*16 + lg*4 + r];
                    float qn[4];
                    #pragma unroll
                    for (int n = 0; n < 4; ++n) {
                        float t = 0.f;
                        #pragma unroll
                        for (int m = 0; m < 4; ++m)
                            #pragma unroll
                            for (int r = 0; r < 4; ++r) t = fmaf(acc[m][n][r], invv[m][r], t);
                        qn[n] = t;
                    }
                    #pragma unroll
                    for (int n = 0; n < 4; ++n) {
                        qn[n] += __shfl_xor(qn[n], 16);
                        qn[n] += __shfl_xor(qn[n], 32);
                    }
                    float* bar =
                        s==2 ? ws + OFF_YBAR  + ((size_t)u  *BB + b)*DD :
                        s==3 ? ws + OFF_XPBAR + ((size_t)px0*BB + b)*DD :
                        s==4 ? ws + OFF_XPBAR + ((size_t)px1*BB + b)*DD :
                        s==5 ? ws + OFF_YPBAR + ((size_t)py0*BB + b)*DD :
                               ws + OFF_YPBAR + ((size_t)py1*BB + b)*DD;
                    if (lane < 16) {
                        #pragma unroll
                        for (int n = 0; n < 4; ++n)
                            atomicAdd(&bar[wq*64 + n*16 + lane], qn[n]);
                    }
                }
            }
            #pragma unroll
            for (int m = 0; m < 4; ++m)
                #pragma unroll
                for (int n = 0; n < 4; ++n) acc[m][n] = (f32x4)0.f;
            ++task;
        }
    }
}

// ---------------------------------------------------------------------------
// Pass 2a: proj[d] = sum_e W[e][d] * (bar[e]/N);  cs = sum_e bias[e]*(bar[e]/N)
// ---------------------------------------------------------------------------
__global__ __launch_bounds__(256) void proj_kernel(
    const float* __restrict__ Wsx, const float* __restrict__ bsx,
    const float* __restrict__ Wpx, const float* __restrict__ bpx,
    const float* __restrict__ Wpy, const float* __restrict__ bpy,
    float* __restrict__ ws)
{
    __shared__ float barl[DD];
    __shared__ float redl[256];
    const int task = blockIdx.x >> 4;
    const int b    = blockIdx.x & 15;
    const int tid  = threadIdx.x;
    const float *W, *bias, *barp;
    float *projp, *csp;
    if (task < 3) {
        const int uu = task;
        W = Wsx + (size_t)uu*DD*DD; bias = bsx + uu*DD;
        barp  = ws + OFF_YBAR  + ((size_t)uu*BB + b)*DD;
        projp = ws + OFF_PROJS + ((size_t)uu*BB + b)*DD;
        csp   = ws + OFF_CSS + uu*BB + b;
    } else if (task < 9) {
        const int p = task - 3; const int i = p>>1;
        const int j = (p&1) == 0 ? (i==0?1:0) : (i==2?1:2);
        W = Wpx + (size_t)(i*NU+j)*DD*DD; bias = bpx + (i*NU+j)*DD;
        barp  = ws + OFF_YPBAR + ((size_t)p*BB + b)*DD;
        projp = ws + OFF_PROJX + ((size_t)p*BB + b)*DD;
        csp   = ws + OFF_CSX + p*BB + b;
    } else {
        const int p = task - 9; const int i = p>>1;
        const int j = (p&1) == 0 ? (i==0?1:0) : (i==2?1:2);
        W = Wpy + (size_t)(i*NU+j)*DD*DD; bias = bpy + (i*NU+j)*DD;
        barp  = ws + OFF_XPBAR + ((size_t)p*BB + b)*DD;
        projp = ws + OFF_PROJY + ((size_t)p*BB + b)*DD;
        csp   = ws + OFF_CSY + p*BB + b;
    }
    barl[tid] = barp[tid] * (1.f / NN);
    __syncthreads();
    float s = 0.f;
    for (int e = 0; e < DD; ++e) s = fmaf(W[(size_t)e*DD + tid], barl[e], s);
    projp[tid] = s;
    redl[tid] = bias[tid] * barl[tid];
    __syncthreads();
    for (int st = 128; st > 0; st >>= 1) {
        if (tid < st) redl[tid] += redl[tid + st];
        __syncthreads();
    }
    if (tid == 0) *csp = redl[0];
}

// ---------------------------------------------------------------------------
// Pass 2b (util-fused): per 32-token tile of util u, dot U rows against the
// 5 proj vectors that have u as source; write 5 potential arrays.
// ---------------------------------------------------------------------------
__global__ __launch_bounds__(256) void pots_kernel(
    const float* __restrict__ u0, const float* __restrict__ u1, const float* __restrict__ u2,
    float* __restrict__ ws)
{
    __shared__ float projl[5][DD];
    __shared__ float csl[5];
    const int u    = blockIdx.y;
    const int row0 = blockIdx.x * 32;
    const int b    = row0 >> 10;
    const int tid  = threadIdx.x;
    const int px0 = u*2, px1 = u*2+1;
    const int py0 = (u==0)?2:((u==1)?0:1);
    const int py1 = (u==0)?4:((u==1)?5:3);

    projl[0][tid] = ws[OFF_PROJS + ((size_t)u  *BB + b)*DD + tid];
    projl[1][tid] = ws[OFF_PROJX + ((size_t)px0*BB + b)*DD + tid];
    projl[2][tid] = ws[OFF_PROJX + ((size_t)px1*BB + b)*DD + tid];
    projl[3][tid] = ws[OFF_PROJY + ((size_t)py0*BB + b)*DD + tid];
    projl[4][tid] = ws[OFF_PROJY + ((size_t)py1*BB + b)*DD + tid];
    if (tid == 0) {
        csl[0] = ws[OFF_CSS + u*BB + b];
        csl[1] = ws[OFF_CSX + px0*BB + b];
        csl[2] = ws[OFF_CSX + px1*BB + b];
        csl[3] = ws[OFF_CSY + py0*BB + b];
        csl[4] = ws[OFF_CSY + py1*BB + b];
    }
    __syncthreads();
    const float* src = selU(u,u0,u1,u2);
    const int token = tid >> 3, q = tid & 7;
    const int row = row0 + token;
    float a0=0.f,a1=0.f,a2=0.f,a3=0.f,a4=0.f;
    #pragma unroll
    for (int cc = 0; cc < 8; ++cc) {
        const int d0 = q*32 + cc*4;
        const float4 v  = *reinterpret_cast<const float4*>(src + (size_t)row*DD + d0);
        const float4 p0 = *reinterpret_cast<const float4*>(&projl[0][d0]);
        const float4 p1 = *reinterpret_cast<const float4*>(&projl[1][d0]);
        const float4 p2 = *reinterpret_cast<const float4*>(&projl[2][d0]);
        const float4 p3 = *reinterpret_cast<const float4*>(&projl[3][d0]);
        const float4 p4 = *reinterpret_cast<const float4*>(&projl[4][d0]);
        a0 = fmaf(v.x,p0.x,fmaf(v.y,p0.y,fmaf(v.z,p0.z,fmaf(v.w,p0.w,a0))));
        a1 = fmaf(v.x,p1.x,fmaf(v.y,p1.y,fmaf(v.z,p1.z,fmaf(v.w,p1.w,a1))));
        a2 = fmaf(v.x,p2.x,fmaf(v.y,p2.y,fmaf(v.z,p2.z,fmaf(v.w,p2.w,a2))));
        a3 = fmaf(v.x,p3.x,fmaf(v.y,p3.y,fmaf(v.z,p3.z,fmaf(v.w,p3.w,a3))));
        a4 = fmaf(v.x,p4.x,fmaf(v.y,p4.y,fmaf(v.z,p4.z,fmaf(v.w,p4.w,a4))));
    }
    #pragma unroll
    for (int mask = 1; mask <= 4; mask <<= 1) {
        a0 += __shfl_xor(a0, mask, 8);
        a1 += __shfl_xor(a1, mask, 8);
        a2 += __shfl_xor(a2, mask, 8);
        a3 += __shfl_xor(a3, mask, 8);
        a4 += __shfl_xor(a4, mask, 8);
    }
    if (q == 0) {
        ws[OFF_SELFP + (size_t)u  *MM + row] = (a0 + csl[0]) * ws[OFF_INVXS + (size_t)u  *MM + row];
        ws[OFF_POTX  + (size_t)px0*MM + row] = (a1 + csl[1]) * ws[OFF_INVXP + (size_t)px0*MM + row];
        ws[OFF_POTX  + (size_t)px1*MM + row] = (a2 + csl[2]) * ws[OFF_INVXP + (size_t)px1*MM + row];
        ws[OFF_POTY  + (size_t)py0*MM + row] = (a3 + csl[3]) * ws[OFF_INVYP + (size_t)py0*MM + row];
        ws[OFF_POTY  + (size_t)py1*MM + row] = (a4 + csl[4]) * ws[OFF_INVYP + (size_t)py1*MM + row];
    }
}

// ---------------------------------------------------------------------------
// Pass 3 (j-fused): per (j,b): logits for i=0..2 -> 3 softmaxes -> one pass
// over Uj accumulating 3 attended features.
// ---------------------------------------------------------------------------
__global__ __launch_bounds__(256) void attend_kernel(
    const float* __restrict__ u0, const float* __restrict__ u1, const float* __restrict__ u2,
    const float* __restrict__ wdiag, const float* __restrict__ wpair,
    const float* __restrict__ ws, float* __restrict__ out)
{
    __shared__ float el[3][NN];
    __shared__ float redl[256];
    const int c = blockIdx.x;          // 0..47
    const int j = c >> 4, b = c & 15;
    const int tid = threadIdx.x;

    #pragma unroll
    for (int i = 0; i < 3; ++i) {
        if (i == j) {
            const int p1 = i*2, p2 = i*2+1;
            const float w0 = wdiag[i*4+0], w1 = wdiag[i*4+1], w2 = wdiag[i*4+2], w3 = wdiag[i*4+3];
            for (int n = tid; n < NN; n += 256) {
                const int row = b*NN + n;
                el[i][n] = w0*ws[OFF_UNARY + i*MM + row] + w1*ws[OFF_SELFP + i*MM + row]
                         + w2*ws[OFF_POTX + p1*MM + row] + w3*ws[OFF_POTX + p2*MM + row];
            }
        } else {
            const int p = i*2 + (j > i ? j-1 : j);
            const float w0 = wpair[(i*3+j)*3+0], w1 = wpair[(i*3+j)*3+1], w2 = wpair[(i*3+j)*3+2];
            for (int n = tid; n < NN; n += 256) {
                const int row = b*NN + n;
                el[i][n] = w0*ws[OFF_UNARY + j*MM + row] + w1*ws[OFF_SELFP + j*MM + row]
                         + w2*ws[OFF_POTY + p*MM + row];
            }
        }
    }
    __syncthreads();
    float invS[3];
    #pragma unroll
    for (int i = 0; i < 3; ++i) {
        float m = -1e30f;
        for (int n = tid; n < NN; n += 256) m = fmaxf(m, el[i][n]);
        redl[tid] = m; __syncthreads();
        for (int st = 128; st > 0; st >>= 1) {
            if (tid < st) redl[tid] = fmaxf(redl[tid], redl[tid+st]);
            __syncthreads();
        }
        m = redl[0];
        __syncthreads();
        float ss = 0.f;
        for (int n = tid; n < NN; n += 256) {
            const float e = expf(el[i][n] - m);
            el[i][n] = e;
            ss += e;
        }
        redl[tid] = ss; __syncthreads();
        for (int st = 128; st > 0; st >>= 1) {
            if (tid < st) redl[tid] += redl[tid+st];
            __syncthreads();
        }
        invS[i] = 1.f / redl[0];
        __syncthreads();
    }

    const float* Uj = selU(j, u0, u1, u2) + (size_t)b*NN*DD;
    float a0 = 0.f, a1 = 0.f, a2 = 0.f;
    #pragma unroll 8
    for (int n = 0; n < NN; ++n) {
        const float v = Uj[(size_t)n*DD + tid];
        a0 = fmaf(el[0][n], v, a0);
        a1 = fmaf(el[1][n], v, a1);
        a2 = fmaf(el[2][n], v, a2);
    }
    out[((size_t)(0*3 + j)*BB + b)*DD + tid] = a0 * invS[0];
    out[((size_t)(1*3 + j)*BB + b)*DD + tid] = a1 * invS[1];
    out[((size_t)(2*3 + j)*BB + b)*DD + tid] = a2 * invS[2];
}

// ---------------------------------------------------------------------------
extern "C" void kernel_launch(void* const* d_in, const int* in_sizes, int n_in,
                              void* d_out, int out_size, void* d_ws, size_t ws_size,
                              hipStream_t stream)
{
    (void)in_sizes; (void)n_in; (void)out_size; (void)ws_size;
    const float* u0    = (const float*)d_in[0];
    const float* u1    = (const float*)d_in[1];
    const float* u2    = (const float*)d_in[2];
    const float* Wu    = (const float*)d_in[3];
    const float* bu    = (const float*)d_in[4];
    const float* wr    = (const float*)d_in[5];
    const float* br    = (const float*)d_in[6];
    const float* Wsx   = (const float*)d_in[7];
    const float* bsx   = (const float*)d_in[8];
    const float* Wsy   = (const float*)d_in[9];
    const float* bsy   = (const float*)d_in[10];
    const float* Wpx   = (const float*)d_in[11];
    const float* bpx   = (const float*)d_in[12];
    const float* Wpy   = (const float*)d_in[13];
    const float* bpy   = (const float*)d_in[14];
    const float* wdiag = (const float*)d_in[15];
    const float* wpair = (const float*)d_in[16];
    float* ws  = (float*)d_ws;
    float* out = (float*)d_out;

    // zero the atomic accumulators (Ybar, Xpbar, Ypbar are contiguous)
    hipMemsetAsync(ws + OFF_YBAR, 0, (size_t)(NU + 2*NPAIR)*BB*DD*sizeof(float), stream);

    dim3 gw(21, 8);
    convw_kernel<<<gw, 256, 0, stream>>>(Wu, Wsx, Wsy, Wpx, Wpy, ws);

    dim3 g1(MM/64, 3);
    pass1_kernel<<<g1, 256, 0, stream>>>(u0,u1,u2,bu,wr,br,bsx,bsy,bpx,bpy,ws);

    proj_kernel<<<15*BB, 256, 0, stream>>>(Wsx,bsx,Wpx,bpx,Wpy,bpy,ws);
    dim3 g2(MM/32, 3);
    pots_kernel<<<g2, 256, 0, stream>>>(u0,u1,u2,ws);
    attend_kernel<<<3*BB, 256, 0, stream>>>(u0,u1,u2,wdiag,wpair,ws,out);
}

// Round 4
// 145.513 us; speedup vs baseline: 4.6409x; 1.1133x over previous
//
#include <hip/hip_runtime.h>
#include <math.h>

#define NU 3
#define BB 16
#define NN 1024
#define DD 256
#define MM (BB*NN)      // 16384 tokens per util
#define NPAIR 6

// workspace layout (float element offsets)
#define OFF_UNARY  0
#define OFF_INVXS  (OFF_UNARY + NU*MM)
#define OFF_INVXP  (OFF_INVXS + NU*MM)
#define OFF_INVYP  (OFF_INVXP + NPAIR*MM)
#define OFF_YBAR   (OFF_INVYP + NPAIR*MM)          // bars contiguous for one memset
#define OFF_XPBAR  (OFF_YBAR + NU*BB*DD)
#define OFF_YPBAR  (OFF_XPBAR + NPAIR*BB*DD)
#define OFF_PROJS  (OFF_YPBAR + NPAIR*BB*DD)
#define OFF_PROJX  (OFF_PROJS + NU*BB*DD)
#define OFF_PROJY  (OFF_PROJX + NPAIR*BB*DD)
#define OFF_CSS    (OFF_PROJY + NPAIR*BB*DD)
#define OFF_CSX    (OFF_CSS + NU*BB)
#define OFF_CSY    (OFF_CSX + NPAIR*BB)
#define OFF_SELFP  (OFF_CSY + NPAIR*BB)
#define OFF_POTX   (OFF_SELFP + NU*MM)
#define OFF_POTY   (OFF_POTX + NPAIR*MM)
#define WS_FLOATS  (OFF_POTY + NPAIR*MM)           // = 663792
// f16 weights, fragment order: 21 slots x 65536 halves = 688128 floats
#define OFF_PROB   (WS_FLOATS + 21*32768)
#define OFF_PART   (OFF_PROB + 9*BB*NN)
// end = OFF_PART + 9*BB*8*DD  (~7.2 MB total)

typedef _Float16 half8 __attribute__((ext_vector_type(8)));
typedef float f32x4 __attribute__((ext_vector_type(4)));

__device__ __forceinline__ const float* selU(int u, const float* u0, const float* u1, const float* u2) {
    return u == 0 ? u0 : (u == 1 ? u1 : u2);
}
__device__ __forceinline__ half8 cvt8(float4 a, float4 b) {
    half8 h = { (_Float16)a.x,(_Float16)a.y,(_Float16)a.z,(_Float16)a.w,
                (_Float16)b.x,(_Float16)b.y,(_Float16)b.z,(_Float16)b.w };
    return h;
}

// ---------------------------------------------------------------------------
// Weight convert: fp32 -> f16, fragment order. Slot (u, s=0..6):
// s0 Wu[u]; s1 Wsx[u]; s2 Wsy[u]; s3/s4 Wpx[u->j0/j1]; s5/s6 Wpy[j0/j1->u].
// Per slot, half index = ((et*8 + kc)*64 + lane)*8 + h, where
// e = et*16 + (lane&15), k = kc*32 + (lane>>4)*8 + h. A wave's bf fragment
// load is then 1KB contiguous.
// ---------------------------------------------------------------------------
__global__ __launch_bounds__(256) void convw_kernel(
    const float* __restrict__ Wu, const float* __restrict__ Wsx, const float* __restrict__ Wsy,
    const float* __restrict__ Wpx, const float* __restrict__ Wpy, float* __restrict__ ws)
{
    const int slot = blockIdx.x;          // 0..20
    const int kc   = blockIdx.y;          // 0..7
    const int tid  = threadIdx.x;
    const int u = slot / 7, s = slot % 7;
    const int j0 = (u==0)?1:0, j1 = (u==2)?1:2;
    const float* W =
        s==0 ? Wu  + (size_t)u*DD*DD :
        s==1 ? Wsx + (size_t)u*DD*DD :
        s==2 ? Wsy + (size_t)u*DD*DD :
        s==3 ? Wpx + (size_t)(u*NU+j0)*DD*DD :
        s==4 ? Wpx + (size_t)(u*NU+j1)*DD*DD :
        s==5 ? Wpy + (size_t)(j0*NU+u)*DD*DD :
               Wpy + (size_t)(j1*NU+u)*DD*DD;
    _Float16* wh = (_Float16*)(ws + WS_FLOATS) + (size_t)slot*65536;
    #pragma unroll
    for (int g = 0; g < 4; ++g) {
        const int idx16 = g*256 + tid;        // 0..1023 = et*64 + lane
        const int et   = idx16 >> 6;
        const int lane = idx16 & 63;
        const int e  = et*16 + (lane & 15);
        const int k0 = kc*32 + (lane >> 4)*8;
        const float* sp = W + (size_t)e*DD + k0;
        const float4 v0 = *reinterpret_cast<const float4*>(sp);
        const float4 v1 = *reinterpret_cast<const float4*>(sp + 4);
        *reinterpret_cast<half8*>(wh + ((size_t)(et*8 + kc)*64 + lane)*8) = cvt8(v0, v1);
    }
}

// ---------------------------------------------------------------------------
// Pass 1: grid (MM/64, 3). Block = 64-token tile of util u, 4 waves, wave wq
// owns e in [wq*64, wq*64+64). U tile f16 LDS-resident (XOR-swizzled); A-frags
// for m=0,1 register-resident; W streamed global->register in fragment order.
// K-loop has NO barriers. 7 tasks, fused epilogues.
// ---------------------------------------------------------------------------
__global__ __launch_bounds__(256, 2) void pass1_kernel(
    const float* __restrict__ u0, const float* __restrict__ u1, const float* __restrict__ u2,
    const float* __restrict__ bu, const float* __restrict__ wr, const float* __restrict__ br,
    const float* __restrict__ bsx, const float* __restrict__ bsy,
    const float* __restrict__ bpx, const float* __restrict__ bpy,
    float* __restrict__ ws)
{
    __shared__ __align__(16) _Float16 Ub[16384];   // [kc=8][tok=64][32k] swizzled
    __shared__ float ep_sum[4][64];
    __shared__ float ep_inv[64];

    const int tid  = threadIdx.x;
    const int u    = blockIdx.y;
    const int row0 = blockIdx.x * 64;
    const int b    = row0 >> 10;

    const int j0 = (u==0)?1:0, j1 = (u==2)?1:2;
    const int px0 = u*2, px1 = u*2+1;
    const int py0 = (u==0)?2:((u==1)?0:1);
    const int py1 = (u==0)?4:((u==1)?5:3);

    const float* src = selU(u,u0,u1,u2);
    const _Float16* whU = (const _Float16*)(ws + WS_FLOATS) + (size_t)u*7*65536;

    const int lane = tid & 63, wq = tid >> 6;
    const int l15 = lane & 15, lg = lane >> 4;
    const int swz = (l15 >> 1) & 3;
    const int kxor = (lg ^ swz) * 8;

    // per-wave W base: fragment (n,kc) at wbase + s*65536 + n*4096 + kc*512
    const _Float16* wbase = whU + (size_t)wq*16384 + (size_t)lane*8;

    f32x4 acc[4][4];
    #pragma unroll
    for (int m = 0; m < 4; ++m)
        #pragma unroll
        for (int n = 0; n < 4; ++n) acc[m][n] = (f32x4)0.f;

    half8 bfA[4], bfB[4], afdA[2], afdB[2];
    half8 af_res[2][8];

#define BFLD(DST, S, KC) { \
    _Pragma("unroll") \
    for (int n_ = 0; n_ < 4; ++n_) \
        DST[n_] = *reinterpret_cast<const half8*>(wbase + (size_t)(S)*65536 + n_*4096 + (KC)*512); }

#define AFLD(DST, KC) { \
    DST[0] = *reinterpret_cast<const half8*>(&Ub[(KC)*2048 + (32 + l15)*32 + kxor]); \
    DST[1] = *reinterpret_cast<const half8*>(&Ub[(KC)*2048 + (48 + l15)*32 + kxor]); }

#define MFMAS(KC, BF, AFD) { \
    _Pragma("unroll") \
    for (int n_ = 0; n_ < 4; ++n_) { \
        acc[0][n_] = __builtin_amdgcn_mfma_f32_16x16x32_f16(af_res[0][KC], BF[n_], acc[0][n_],0,0,0); \
        acc[1][n_] = __builtin_amdgcn_mfma_f32_16x16x32_f16(af_res[1][KC], BF[n_], acc[1][n_],0,0,0); \
        acc[2][n_] = __builtin_amdgcn_mfma_f32_16x16x32_f16(AFD[0],        BF[n_], acc[2][n_],0,0,0); \
        acc[3][n_] = __builtin_amdgcn_mfma_f32_16x16x32_f16(AFD[1],        BF[n_], acc[3][n_],0,0,0); } }

#define SLAB(KC, BFC, BFN, AFC, AFN) { \
    if ((KC) < 7) { BFLD(BFN, s, (KC)+1) } else if (s < 6) { BFLD(BFN, s+1, 0) } \
    if ((KC) < 7) { AFLD(AFN, (KC)+1) } else { AFLD(AFN, 0) } \
    MFMAS(KC, BFC, AFC) }

    // issue first W fragment loads early (hide under U staging)
    BFLD(bfA, 0, 0)

    // U prologue: 64 tok x 256 k fp32 -> f16 swizzled LDS (once per block)
    #pragma unroll
    for (int c = 0; c < 8; ++c) {
        const int G2 = c*256 + tid;          // 0..2047
        const int t  = G2 >> 5;              // token 0..63
        const int gk = G2 & 31;              // k-granule 0..31
        const int kc = gk >> 2, kg = gk & 3;
        const float* p = src + (size_t)(row0 + t)*DD + gk*8;
        const float4 v0 = *reinterpret_cast<const float4*>(p);
        const float4 v1 = *reinterpret_cast<const float4*>(p + 4);
        const int kgs = kg ^ ((t >> 1) & 3);
        *reinterpret_cast<half8*>(&Ub[kc*2048 + t*32 + kgs*8]) = cvt8(v0, v1);
    }
    __syncthreads();

    // register-resident A fragments (m=0,1) for all kc
    #pragma unroll
    for (int kc = 0; kc < 8; ++kc) {
        af_res[0][kc] = *reinterpret_cast<const half8*>(&Ub[kc*2048 + (l15)*32 + kxor]);
        af_res[1][kc] = *reinterpret_cast<const half8*>(&Ub[kc*2048 + (16 + l15)*32 + kxor]);
    }
    AFLD(afdA, 0)

    for (int s = 0; s < 7; ++s) {
        SLAB(0, bfA, bfB, afdA, afdB)
        SLAB(1, bfB, bfA, afdB, afdA)
        SLAB(2, bfA, bfB, afdA, afdB)
        SLAB(3, bfB, bfA, afdB, afdA)
        SLAB(4, bfA, bfB, afdA, afdB)
        SLAB(5, bfB, bfA, afdB, afdA)
        SLAB(6, bfA, bfB, afdA, afdB)
        SLAB(7, bfB, bfA, afdB, afdA)

        // ================= epilogue for task s =================
        const float* bias =
            s==0 ? bu  + u*DD :
            s==1 ? bsx + u*DD :
            s==2 ? bsy + u*DD :
            s==3 ? bpx + (u*NU+j0)*DD :
            s==4 ? bpx + (u*NU+j1)*DD :
            s==5 ? bpy + (j0*NU+u)*DD :
                   bpy + (j1*NU+u)*DD;
        float bv[4];
        #pragma unroll
        for (int n = 0; n < 4; ++n) bv[n] = bias[wq*64 + n*16 + l15];
        #pragma unroll
        for (int m = 0; m < 4; ++m)
            #pragma unroll
            for (int n = 0; n < 4; ++n)
                #pragma unroll
                for (int r = 0; r < 4; ++r) acc[m][n][r] += bv[n];

        if (s == 0) {
            float wrv[4];
            #pragma unroll
            for (int n = 0; n < 4; ++n) wrv[n] = wr[u*DD + wq*64 + n*16 + l15];
            float pm[4][4];
            #pragma unroll
            for (int m = 0; m < 4; ++m)
                #pragma unroll
                for (int r = 0; r < 4; ++r) {
                    float t = 0.f;
                    #pragma unroll
                    for (int n = 0; n < 4; ++n) t = fmaf(fmaxf(acc[m][n][r], 0.f), wrv[n], t);
                    pm[m][r] = t;
                }
            #pragma unroll
            for (int mask = 1; mask <= 8; mask <<= 1)
                #pragma unroll
                for (int m = 0; m < 4; ++m)
                    #pragma unroll
                    for (int r = 0; r < 4; ++r) pm[m][r] += __shfl_xor(pm[m][r], mask);
            if (l15 == 0) {
                #pragma unroll
                for (int m = 0; m < 4; ++m)
                    #pragma unroll
                    for (int r = 0; r < 4; ++r) ep_sum[wq][m*16 + lg*4 + r] = pm[m][r];
            }
            __syncthreads();
            if (tid < 64)
                ws[OFF_UNARY + (size_t)u*MM + row0 + tid] =
                    ep_sum[0][tid]+ep_sum[1][tid]+ep_sum[2][tid]+ep_sum[3][tid] + br[u];
        } else {
            float pm[4][4];
            #pragma unroll
            for (int m = 0; m < 4; ++m)
                #pragma unroll
                for (int r = 0; r < 4; ++r) {
                    float t = 0.f;
                    #pragma unroll
                    for (int n = 0; n < 4; ++n) t = fmaf(acc[m][n][r], acc[m][n][r], t);
                    pm[m][r] = t;
                }
            #pragma unroll
            for (int mask = 1; mask <= 8; mask <<= 1)
                #pragma unroll
                for (int m = 0; m < 4; ++m)
                    #pragma unroll
                    for (int r = 0; r < 4; ++r) pm[m][r] += __shfl_xor(pm[m][r], mask);
            if (l15 == 0) {
                #pragma unroll
                for (int m = 0; m < 4; ++m)
                    #pragma unroll
                    for (int r = 0; r < 4; ++r) ep_sum[wq][m*16 + lg*4 + r] = pm[m][r];
            }
            __syncthreads();
            if (tid < 64) {
                const float ssum = ep_sum[0][tid]+ep_sum[1][tid]+ep_sum[2][tid]+ep_sum[3][tid];
                const float inv = 1.f / fmaxf(sqrtf(ssum), 1e-12f);
                ep_inv[tid] = inv;
                if (s == 1)      ws[OFF_INVXS + (size_t)u  *MM + row0 + tid] = inv;
                else if (s == 3) ws[OFF_INVXP + (size_t)px0*MM + row0 + tid] = inv;
                else if (s == 4) ws[OFF_INVXP + (size_t)px1*MM + row0 + tid] = inv;
                else if (s == 5) ws[OFF_INVYP + (size_t)py0*MM + row0 + tid] = inv;
                else if (s == 6) ws[OFF_INVYP + (size_t)py1*MM + row0 + tid] = inv;
            }
            __syncthreads();
            if (s >= 2) {
                float invv[4][4];
                #pragma unroll
                for (int m = 0; m < 4; ++m)
                    #pragma unroll
                    for (int r = 0; r < 4; ++r) invv[m][r] = ep_inv[m*16 + lg*4 + r];
                float qn[4];
                #pragma unroll
                for (int n = 0; n < 4; ++n) {
                    float t = 0.f;
                    #pragma unroll
                    for (int m = 0; m < 4; ++m)
                        #pragma unroll
                        for (int r = 0; r < 4; ++r) t = fmaf(acc[m][n][r], invv[m][r], t);
                    qn[n] = t;
                }
                #pragma unroll
                for (int n = 0; n < 4; ++n) {
                    qn[n] += __shfl_xor(qn[n], 16);
                    qn[n] += __shfl_xor(qn[n], 32);
                }
                float* bar =
                    s==2 ? ws + OFF_YBAR  + ((size_t)u  *BB + b)*DD :
                    s==3 ? ws + OFF_XPBAR + ((size_t)px0*BB + b)*DD :
                    s==4 ? ws + OFF_XPBAR + ((size_t)px1*BB + b)*DD :
                    s==5 ? ws + OFF_YPBAR + ((size_t)py0*BB + b)*DD :
                           ws + OFF_YPBAR + ((size_t)py1*BB + b)*DD;
                if (lane < 16) {
                    #pragma unroll
                    for (int n = 0; n < 4; ++n)
                        atomicAdd(&bar[wq*64 + n*16 + lane], qn[n]);
                }
            }
        }
        #pragma unroll
        for (int m = 0; m < 4; ++m)
            #pragma unroll
            for (int n = 0; n < 4; ++n) acc[m][n] = (f32x4)0.f;
        __syncthreads();   // protect ep_sum/ep_inv reuse next task
    }
#undef BFLD
#undef AFLD
#undef MFMAS
#undef SLAB
}

// ---------------------------------------------------------------------------
// Pass 2a: proj[d] = sum_e W[e][d] * (bar[e]/N);  cs = sum_e bias[e]*(bar[e]/N)
// ---------------------------------------------------------------------------
__global__ __launch_bounds__(256) void proj_kernel(
    const float* __restrict__ Wsx, const float* __restrict__ bsx,
    const float* __restrict__ Wpx, const float* __restrict__ bpx,
    const float* __restrict__ Wpy, const float* __restrict__ bpy,
    float* __restrict__ ws)
{
    __shared__ float barl[DD];
    __shared__ float redl[256];
    const int task = blockIdx.x >> 4;
    const int b    = blockIdx.x & 15;
    const int tid  = threadIdx.x;
    const float *W, *bias, *barp;
    float *projp, *csp;
    if (task < 3) {
        const int uu = task;
        W = Wsx + (size_t)uu*DD*DD; bias = bsx + uu*DD;
        barp  = ws + OFF_YBAR  + ((size_t)uu*BB + b)*DD;
        projp = ws + OFF_PROJS + ((size_t)uu*BB + b)*DD;
        csp   = ws + OFF_CSS + uu*BB + b;
    } else if (task < 9) {
        const int p = task - 3; const int i = p>>1;
        const int j = (p&1) == 0 ? (i==0?1:0) : (i==2?1:2);
        W = Wpx + (size_t)(i*NU+j)*DD*DD; bias = bpx + (i*NU+j)*DD;
        barp  = ws + OFF_YPBAR + ((size_t)p*BB + b)*DD;
        projp = ws + OFF_PROJX + ((size_t)p*BB + b)*DD;
        csp   = ws + OFF_CSX + p*BB + b;
    } else {
        const int p = task - 9; const int i = p>>1;
        const int j = (p&1) == 0 ? (i==0?1:0) : (i==2?1:2);
        W = Wpy + (size_t)(i*NU+j)*DD*DD; bias = bpy + (i*NU+j)*DD;
        barp  = ws + OFF_XPBAR + ((size_t)p*BB + b)*DD;
        projp = ws + OFF_PROJY + ((size_t)p*BB + b)*DD;
        csp   = ws + OFF_CSY + p*BB + b;
    }
    barl[tid] = barp[tid] * (1.f / NN);
    __syncthreads();
    float s = 0.f;
    for (int e = 0; e < DD; ++e) s = fmaf(W[(size_t)e*DD + tid], barl[e], s);
    projp[tid] = s;
    redl[tid] = bias[tid] * barl[tid];
    __syncthreads();
    for (int st = 128; st > 0; st >>= 1) {
        if (tid < st) redl[tid] += redl[tid + st];
        __syncthreads();
    }
    if (tid == 0) *csp = redl[0];
}

// ---------------------------------------------------------------------------
// Pass 2b (util-fused): per 32-token tile of util u, dot U rows against the
// 5 proj vectors that have u as source; write 5 potential arrays.
// ---------------------------------------------------------------------------
__global__ __launch_bounds__(256) void pots_kernel(
    const float* __restrict__ u0, const float* __restrict__ u1, const float* __restrict__ u2,
    float* __restrict__ ws)
{
    __shared__ float projl[5][DD];
    __shared__ float csl[5];
    const int u    = blockIdx.y;
    const int row0 = blockIdx.x * 32;
    const int b    = row0 >> 10;
    const int tid  = threadIdx.x;
    const int px0 = u*2, px1 = u*2+1;
    const int py0 = (u==0)?2:((u==1)?0:1);
    const int py1 = (u==0)?4:((u==1)?5:3);

    projl[0][tid] = ws[OFF_PROJS + ((size_t)u  *BB + b)*DD + tid];
    projl[1][tid] = ws[OFF_PROJX + ((size_t)px0*BB + b)*DD + tid];
    projl[2][tid] = ws[OFF_PROJX + ((size_t)px1*BB + b)*DD + tid];
    projl[3][tid] = ws[OFF_PROJY + ((size_t)py0*BB + b)*DD + tid];
    projl[4][tid] = ws[OFF_PROJY + ((size_t)py1*BB + b)*DD + tid];
    if (tid == 0) {
        csl[0] = ws[OFF_CSS + u*BB + b];
        csl[1] = ws[OFF_CSX + px0*BB + b];
        csl[2] = ws[OFF_CSX + px1*BB + b];
        csl[3] = ws[OFF_CSY + py0*BB + b];
        csl[4] = ws[OFF_CSY + py1*BB + b];
    }
    __syncthreads();
    const float* src = selU(u,u0,u1,u2);
    const int token = tid >> 3, q = tid & 7;
    const int row = row0 + token;
    float a0=0.f,a1=0.f,a2=0.f,a3=0.f,a4=0.f;
    #pragma unroll
    for (int cc = 0; cc < 8; ++cc) {
        const int d0 = q*32 + cc*4;
        const float4 v  = *reinterpret_cast<const float4*>(src + (size_t)row*DD + d0);
        const float4 p0 = *reinterpret_cast<const float4*>(&projl[0][d0]);
        const float4 p1 = *reinterpret_cast<const float4*>(&projl[1][d0]);
        const float4 p2 = *reinterpret_cast<const float4*>(&projl[2][d0]);
        const float4 p3 = *reinterpret_cast<const float4*>(&projl[3][d0]);
        const float4 p4 = *reinterpret_cast<const float4*>(&projl[4][d0]);
        a0 = fmaf(v.x,p0.x,fmaf(v.y,p0.y,fmaf(v.z,p0.z,fmaf(v.w,p0.w,a0))));
        a1 = fmaf(v.x,p1.x,fmaf(v.y,p1.y,fmaf(v.z,p1.z,fmaf(v.w,p1.w,a1))));
        a2 = fmaf(v.x,p2.x,fmaf(v.y,p2.y,fmaf(v.z,p2.z,fmaf(v.w,p2.w,a2))));
        a3 = fmaf(v.x,p3.x,fmaf(v.y,p3.y,fmaf(v.z,p3.z,fmaf(v.w,p3.w,a3))));
        a4 = fmaf(v.x,p4.x,fmaf(v.y,p4.y,fmaf(v.z,p4.z,fmaf(v.w,p4.w,a4))));
    }
    #pragma unroll
    for (int mask = 1; mask <= 4; mask <<= 1) {
        a0 += __shfl_xor(a0, mask, 8);
        a1 += __shfl_xor(a1, mask, 8);
        a2 += __shfl_xor(a2, mask, 8);
        a3 += __shfl_xor(a3, mask, 8);
        a4 += __shfl_xor(a4, mask, 8);
    }
    if (q == 0) {
        ws[OFF_SELFP + (size_t)u  *MM + row] = (a0 + csl[0]) * ws[OFF_INVXS + (size_t)u  *MM + row];
        ws[OFF_POTX  + (size_t)px0*MM + row] = (a1 + csl[1]) * ws[OFF_INVXP + (size_t)px0*MM + row];
        ws[OFF_POTX  + (size_t)px1*MM + row] = (a2 + csl[2]) * ws[OFF_INVXP + (size_t)px1*MM + row];
        ws[OFF_POTY  + (size_t)py0*MM + row] = (a3 + csl[3]) * ws[OFF_INVYP + (size_t)py0*MM + row];
        ws[OFF_POTY  + (size_t)py1*MM + row] = (a4 + csl[4]) * ws[OFF_INVYP + (size_t)py1*MM + row];
    }
}

// ---------------------------------------------------------------------------
// Pass 3a: per (j,b): logits for i=0..2 -> softmax -> normalized probs to ws
// ---------------------------------------------------------------------------
__global__ __launch_bounds__(256) void attend_logits_kernel(
    const float* __restrict__ wdiag, const float* __restrict__ wpair,
    float* __restrict__ ws)
{
    __shared__ float el[3][NN];
    __shared__ float redl[256];
    const int c = blockIdx.x;          // 0..47
    const int j = c >> 4, b = c & 15;
    const int tid = threadIdx.x;

    #pragma unroll
    for (int i = 0; i < 3; ++i) {
        if (i == j) {
            const int p1 = i*2, p2 = i*2+1;
            const float w0 = wdiag[i*4+0], w1 = wdiag[i*4+1], w2 = wdiag[i*4+2], w3 = wdiag[i*4+3];
            for (int n = tid; n < NN; n += 256) {
                const int row = b*NN + n;
                el[i][n] = w0*ws[OFF_UNARY + i*MM + row] + w1*ws[OFF_SELFP + i*MM + row]
                         + w2*ws[OFF_POTX + p1*MM + row] + w3*ws[OFF_POTX + p2*MM + row];
            }
        } else {
            const int p = i*2 + (j > i ? j-1 : j);
            const float w0 = wpair[(i*3+j)*3+0], w1 = wpair[(i*3+j)*3+1], w2 = wpair[(i*3+j)*3+2];
            for (int n = tid; n < NN; n += 256) {
                const int row = b*NN + n;
                el[i][n] = w0*ws[OFF_UNARY + j*MM + row] + w1*ws[OFF_SELFP + j*MM + row]
                         + w2*ws[OFF_POTY + p*MM + row];
            }
        }
    }
    __syncthreads();
    #pragma unroll
    for (int i = 0; i < 3; ++i) {
        float m = -1e30f;
        for (int n = tid; n < NN; n += 256) m = fmaxf(m, el[i][n]);
        redl[tid] = m; __syncthreads();
        for (int st = 128; st > 0; st >>= 1) {
            if (tid < st) redl[tid] = fmaxf(redl[tid], redl[tid+st]);
            __syncthreads();
        }
        m = redl[0];
        __syncthreads();
        float ss = 0.f;
        for (int n = tid; n < NN; n += 256) {
            const float e = expf(el[i][n] - m);
            el[i][n] = e;
            ss += e;
        }
        redl[tid] = ss; __syncthreads();
        for (int st = 128; st > 0; st >>= 1) {
            if (tid < st) redl[tid] += redl[tid+st];
            __syncthreads();
        }
        const float invS = 1.f / redl[0];
        __syncthreads();
        for (int n = tid; n < NN; n += 256)
            ws[OFF_PROB + ((size_t)(i*3+j)*BB + b)*NN + n] = el[i][n] * invS;
    }
}

// ---------------------------------------------------------------------------
// Pass 3b: chunked weighted sum: partial[(i,j,b)][chunk][d]
// ---------------------------------------------------------------------------
__global__ __launch_bounds__(256) void attend_sum_kernel(
    const float* __restrict__ u0, const float* __restrict__ u1, const float* __restrict__ u2,
    const float* __restrict__ ws, float* __restrict__ wso)
{
    __shared__ float pl[3][128];
    const int x  = blockIdx.x;         // 0..383
    const int jb = x >> 3, ch = x & 7;
    const int j = jb >> 4, b = jb & 15;
    const int tid = threadIdx.x;

    for (int t = tid; t < 384; t += 256) {
        const int i = t >> 7, n = t & 127;
        pl[i][n] = ws[OFF_PROB + ((size_t)(i*3+j)*BB + b)*NN + ch*128 + n];
    }
    __syncthreads();
    const float* Uj = selU(j, u0, u1, u2) + ((size_t)b*NN + ch*128)*DD;
    float a0 = 0.f, a1 = 0.f, a2 = 0.f;
    #pragma unroll 4
    for (int n = 0; n < 128; ++n) {
        const float v = Uj[(size_t)n*DD + tid];
        a0 = fmaf(pl[0][n], v, a0);
        a1 = fmaf(pl[1][n], v, a1);
        a2 = fmaf(pl[2][n], v, a2);
    }
    wso[OFF_PART + (((size_t)(0*3+j)*BB + b)*8 + ch)*DD + tid] = a0;
    wso[OFF_PART + (((size_t)(1*3+j)*BB + b)*8 + ch)*DD + tid] = a1;
    wso[OFF_PART + (((size_t)(2*3+j)*BB + b)*8 + ch)*DD + tid] = a2;
}

// ---------------------------------------------------------------------------
// Pass 3c: reduce chunks -> out
// ---------------------------------------------------------------------------
__global__ __launch_bounds__(256) void attend_reduce_kernel(
    const float* __restrict__ ws, float* __restrict__ out)
{
    const int ijb = blockIdx.x;        // 0..143
    const int tid = threadIdx.x;
    float s = 0.f;
    #pragma unroll
    for (int ch = 0; ch < 8; ++ch)
        s += ws[OFF_PART + ((size_t)ijb*8 + ch)*DD + tid];
    out[(size_t)ijb*DD + tid] = s;
}

// ---------------------------------------------------------------------------
extern "C" void kernel_launch(void* const* d_in, const int* in_sizes, int n_in,
                              void* d_out, int out_size, void* d_ws, size_t ws_size,
                              hipStream_t stream)
{
    (void)in_sizes; (void)n_in; (void)out_size; (void)ws_size;
    const float* u0    = (const float*)d_in[0];
    const float* u1    = (const float*)d_in[1];
    const float* u2    = (const float*)d_in[2];
    const float* Wu    = (const float*)d_in[3];
    const float* bu    = (const float*)d_in[4];
    const float* wr    = (const float*)d_in[5];
    const float* br    = (const float*)d_in[6];
    const float* Wsx   = (const float*)d_in[7];
    const float* bsx   = (const float*)d_in[8];
    const float* Wsy   = (const float*)d_in[9];
    const float* bsy   = (const float*)d_in[10];
    const float* Wpx   = (const float*)d_in[11];
    const float* bpx   = (const float*)d_in[12];
    const float* Wpy   = (const float*)d_in[13];
    const float* bpy   = (const float*)d_in[14];
    const float* wdiag = (const float*)d_in[15];
    const float* wpair = (const float*)d_in[16];
    float* ws  = (float*)d_ws;
    float* out = (float*)d_out;

    // zero the atomic accumulators (Ybar, Xpbar, Ypbar are contiguous)
    hipMemsetAsync(ws + OFF_YBAR, 0, (size_t)(NU + 2*NPAIR)*BB*DD*sizeof(float), stream);

    dim3 gw(21, 8);
    convw_kernel<<<gw, 256, 0, stream>>>(Wu, Wsx, Wsy, Wpx, Wpy, ws);

    dim3 g1(MM/64, 3);
    pass1_kernel<<<g1, 256, 0, stream>>>(u0,u1,u2,bu,wr,br,bsx,bsy,bpx,bpy,ws);

    proj_kernel<<<15*BB, 256, 0, stream>>>(Wsx,bsx,Wpx,bpx,Wpy,bpy,ws);
    dim3 g2(MM/32, 3);
    pots_kernel<<<g2, 256, 0, stream>>>(u0,u1,u2,ws);

    attend_logits_kernel<<<3*BB, 256, 0, stream>>>(wdiag, wpair, ws);
    attend_sum_kernel<<<3*BB*8, 256, 0, stream>>>(u0,u1,u2, ws, ws);
    attend_reduce_kernel<<<9*BB, 256, 0, stream>>>(ws, out);
}